// Round 3
// baseline (411.135 us; speedup 1.0000x reference)
//
#include <hip/hip_runtime.h>
#include <math.h>
#include <float.h>

// Problem constants (from reference setup_inputs)
#define NROWS  16384   // B*K = 256*64
#define DIN    256
#define DBASIS 512
#define CCODES 1024
#define KTOP   8
#define NCAND  16      // refine margin: approx top-16 always contains exact top-8
#define TEMP_F 0.1f

typedef __attribute__((ext_vector_type(8))) short short8v;  // 8 x bf16 (4 VGPRs)
typedef __attribute__((ext_vector_type(4))) float f32x4;    // MFMA C/D

__device__ __forceinline__ unsigned short bf16_rne(float f) {
    unsigned int u = __float_as_uint(f);
    u += 0x7FFFu + ((u >> 16) & 1u);
    return (unsigned short)(u >> 16);
}
__device__ __forceinline__ float bf16_to_f32(unsigned short h) {
    return __uint_as_float(((unsigned int)h) << 16);
}

// ---------------------------------------------------------------------------
// Prep: embed row norms, Eh/El bf16 split, zero usage + vq accumulator
// ---------------------------------------------------------------------------
__global__ __launch_bounds__(256) void k_prep(const float* __restrict__ embed,
                                              unsigned short* __restrict__ Eh,
                                              unsigned short* __restrict__ El,
                                              float* __restrict__ en2,
                                              float* __restrict__ usage,
                                              float* __restrict__ vq_accum) {
    const int c = blockIdx.x * 256 + threadIdx.x;   // grid exactly CCODES threads
    const float4* row = (const float4*)(embed + (size_t)c * DBASIS);
    ushort4* ehr = (ushort4*)(Eh + (size_t)c * DBASIS);
    ushort4* elr = (ushort4*)(El + (size_t)c * DBASIS);
    float s = 0.f;
    #pragma unroll 4
    for (int j = 0; j < DBASIS / 4; ++j) {
        const float4 v = row[j];
        s += v.x * v.x + v.y * v.y + v.z * v.z + v.w * v.w;
        ushort4 h, l;
        h.x = bf16_rne(v.x); l.x = bf16_rne(v.x - bf16_to_f32(h.x));
        h.y = bf16_rne(v.y); l.y = bf16_rne(v.y - bf16_to_f32(h.y));
        h.z = bf16_rne(v.z); l.z = bf16_rne(v.z - bf16_to_f32(h.z));
        h.w = bf16_rne(v.w); l.w = bf16_rne(v.w - bf16_to_f32(h.w));
        ehr[j] = h; elr[j] = l;
    }
    en2[c] = s;
    usage[c] = 0.f;
    if (c == 0) vq_accum[0] = 0.f;
}

// ---------------------------------------------------------------------------
// GEMM 1 (NN, f32 VALU): Z = slot @ W + b.  M=16384,N=512,K=256.
// 128x128 tile, BK=16, 8x8 micro-tile in quadrants. Epilogue also emits the
// bf16 hi/lo split of Z (feeds the MFMA distance GEMM).
// ---------------------------------------------------------------------------
__global__ __launch_bounds__(256, 2) void k_gemm_z(const float* __restrict__ A,
                                                   const float* __restrict__ Bm,
                                                   const float* __restrict__ bias,
                                                   float* __restrict__ Z,
                                                   unsigned short* __restrict__ Zh,
                                                   unsigned short* __restrict__ Zl) {
    __shared__ float As[16][132];
    __shared__ float Bs[16][132];
    const int tid = threadIdx.x;
    const int bm = blockIdx.x * 128;
    const int bn = blockIdx.y * 128;
    const int tx = tid & 15, ty = tid >> 4;
    float acc[2][2][4][4] = {};

    for (int k0 = 0; k0 < DIN; k0 += 16) {
        #pragma unroll
        for (int it = 0; it < 2; ++it) {
            const int r  = (tid >> 2) + it * 64;
            const int c4 = (tid & 3) * 4;
            const float4 a = *(const float4*)(A + (size_t)(bm + r) * DIN + k0 + c4);
            As[c4 + 0][r] = a.x; As[c4 + 1][r] = a.y;
            As[c4 + 2][r] = a.z; As[c4 + 3][r] = a.w;
        }
        {
            const int r  = tid >> 4;
            const int c8 = (tid & 15) * 8;
            const float4 b0 = *(const float4*)(Bm + (size_t)(k0 + r) * DBASIS + bn + c8);
            const float4 b1 = *(const float4*)(Bm + (size_t)(k0 + r) * DBASIS + bn + c8 + 4);
            *(float4*)&Bs[r][c8]     = b0;
            *(float4*)&Bs[r][c8 + 4] = b1;
        }
        __syncthreads();
        #pragma unroll
        for (int kk = 0; kk < 16; ++kk) {
            const float4 a0 = *(const float4*)&As[kk][ty * 4];
            const float4 a1 = *(const float4*)&As[kk][64 + ty * 4];
            const float4 b0 = *(const float4*)&Bs[kk][tx * 4];
            const float4 b1 = *(const float4*)&Bs[kk][64 + tx * 4];
            const float av[2][4] = {{a0.x, a0.y, a0.z, a0.w}, {a1.x, a1.y, a1.z, a1.w}};
            const float bv[2][4] = {{b0.x, b0.y, b0.z, b0.w}, {b1.x, b1.y, b1.z, b1.w}};
            #pragma unroll
            for (int qi = 0; qi < 2; ++qi)
                #pragma unroll
                for (int qj = 0; qj < 2; ++qj)
                    #pragma unroll
                    for (int i = 0; i < 4; ++i)
                        #pragma unroll
                        for (int j = 0; j < 4; ++j)
                            acc[qi][qj][i][j] = fmaf(av[qi][i], bv[qj][j], acc[qi][qj][i][j]);
        }
        __syncthreads();
    }
    #pragma unroll
    for (int qj = 0; qj < 2; ++qj) {
        const int colb = bn + qj * 64 + tx * 4;
        const float4 bv = *(const float4*)(bias + colb);
        const float bb[4] = {bv.x, bv.y, bv.z, bv.w};
        #pragma unroll
        for (int qi = 0; qi < 2; ++qi)
            #pragma unroll
            for (int i = 0; i < 4; ++i) {
                const int row = bm + qi * 64 + ty * 4 + i;
                float4 o;
                o.x = acc[qi][qj][i][0] + bb[0];
                o.y = acc[qi][qj][i][1] + bb[1];
                o.z = acc[qi][qj][i][2] + bb[2];
                o.w = acc[qi][qj][i][3] + bb[3];
                *(float4*)(Z + (size_t)row * DBASIS + colb) = o;
                ushort4 h, l;
                h.x = bf16_rne(o.x); l.x = bf16_rne(o.x - bf16_to_f32(h.x));
                h.y = bf16_rne(o.y); l.y = bf16_rne(o.y - bf16_to_f32(h.y));
                h.z = bf16_rne(o.z); l.z = bf16_rne(o.z - bf16_to_f32(h.z));
                h.w = bf16_rne(o.w); l.w = bf16_rne(o.w - bf16_to_f32(h.w));
                *(ushort4*)(Zh + (size_t)row * DBASIS + colb) = h;
                *(ushort4*)(Zl + (size_t)row * DBASIS + colb) = l;
            }
    }
}

// ---------------------------------------------------------------------------
// GEMM 2 (MFMA bf16-split): Papprox[m][c] = en2[c] - 2*(Zh.Eh + Zh.El + Zl.Eh)
// M=16384, N=1024, Keff=3*512. 128x128 tile, BK=32, 4 waves (2x2, 64x64 each),
// mfma_f32_16x16x32_bf16. LDS layout: granule gi = g*128 + row -> 16B at
// gi*16 (g = k-octet), matches global_load_lds linear-dest rule; fragment
// ds_read_b128 is 2-way bank-aliased (free, m136).
// A-frag lane l: A[row=l&15][k=8*(l>>4)+i]; B-frag lane l: B[k=8*(l>>4)+i][col=l&15]
// C/D lane l reg r: row=(l>>4)*4+r, col=l&15  [m89-verified]
// ---------------------------------------------------------------------------
__global__ __launch_bounds__(256, 2) void k_gemm_p(const unsigned short* __restrict__ Zh,
                                                   const unsigned short* __restrict__ Zl,
                                                   const unsigned short* __restrict__ Eh,
                                                   const unsigned short* __restrict__ El,
                                                   const float* __restrict__ en2,
                                                   float* __restrict__ P) {
    __shared__ __align__(16) short ldsA[4096];  // 8 KB
    __shared__ __align__(16) short ldsB[4096];  // 8 KB
    const int tid  = threadIdx.x;
    const int lane = tid & 63;
    const int w    = tid >> 6;
    const int wr   = w >> 1, wc = w & 1;
    const int bm   = blockIdx.x * 128;
    const int bc   = blockIdx.y * 128;

    f32x4 acc[4][4];
    #pragma unroll
    for (int i = 0; i < 4; ++i)
        #pragma unroll
        for (int j = 0; j < 4; ++j)
            acc[i][j] = (f32x4){0.f, 0.f, 0.f, 0.f};

    for (int ch = 0; ch < 48; ++ch) {
        const int term = ch >> 4;            // 0: Zh.Eh  1: Zh.El  2: Zl.Eh
        const int k0   = (ch & 15) * 32;
        const unsigned short* Asrc = (term == 2) ? Zl : Zh;
        const unsigned short* Bsrc = (term == 1) ? El : Eh;
        #pragma unroll
        for (int j = 0; j < 2; ++j) {
            const int gi = j * 256 + tid;    // granule: g = gi>>7 (k-octet), r = gi&127
            const int g  = gi >> 7;
            const int r  = gi & 127;
            const unsigned short* ga = Asrc + (size_t)(bm + r) * DBASIS + k0 + g * 8;
            const unsigned short* gb = Bsrc + (size_t)(bc + r) * DBASIS + k0 + g * 8;
            __builtin_amdgcn_global_load_lds((const __attribute__((address_space(1))) void*)ga,
                                             (__attribute__((address_space(3))) void*)(&ldsA[gi * 8]),
                                             16, 0, 0);
            __builtin_amdgcn_global_load_lds((const __attribute__((address_space(1))) void*)gb,
                                             (__attribute__((address_space(3))) void*)(&ldsB[gi * 8]),
                                             16, 0, 0);
        }
        __syncthreads();   // drains vmcnt(0) then barrier

        const int kg = lane >> 4;   // k-octet 0..3
        const int lr = lane & 15;
        short8v af[4], bf[4];
        #pragma unroll
        for (int f = 0; f < 4; ++f) {
            af[f] = *(const short8v*)&ldsA[(kg * 128 + wr * 64 + f * 16 + lr) * 8];
            bf[f] = *(const short8v*)&ldsB[(kg * 128 + wc * 64 + f * 16 + lr) * 8];
        }
        #pragma unroll
        for (int fm = 0; fm < 4; ++fm)
            #pragma unroll
            for (int fn = 0; fn < 4; ++fn)
                acc[fm][fn] = __builtin_amdgcn_mfma_f32_16x16x32_bf16(af[fm], bf[fn], acc[fm][fn], 0, 0, 0);
        __syncthreads();   // protect LDS before next stage
    }

    // epilogue: P = en2[col] - 2*acc (row-constant zn2 omitted; added in refine)
    #pragma unroll
    for (int fn = 0; fn < 4; ++fn) {
        const int col = bc + wc * 64 + fn * 16 + (lane & 15);
        const float e2 = en2[col];
        #pragma unroll
        for (int fm = 0; fm < 4; ++fm) {
            const int row0 = bm + wr * 64 + fm * 16 + (lane >> 4) * 4;
            #pragma unroll
            for (int r = 0; r < 4; ++r)
                P[(size_t)(row0 + r) * CCODES + col] = e2 - 2.f * acc[fm][fn][r];
        }
    }
}

// ---------------------------------------------------------------------------
// Top-k: approx top-16 from P, exact f32 refine of the 16 candidates,
// exact top-8 + softmax + q gather + vq/usage. One wave per row.
// ---------------------------------------------------------------------------
__global__ __launch_bounds__(256) void k_topk(const float* __restrict__ P,
                                              const float* __restrict__ Z,
                                              const float* __restrict__ embed,
                                              const float* __restrict__ en2,
                                              float* __restrict__ q_out,
                                              float* __restrict__ idx_out,
                                              float* __restrict__ usage,
                                              float* __restrict__ vq_accum) {
    const int tid  = threadIdx.x;
    const int lane = tid & 63;
    const int w    = tid >> 6;
    const int n    = blockIdx.x * 4 + w;

    // approx scores (coalesced)
    float v[16];
    #pragma unroll
    for (int j = 0; j < 16; ++j) v[j] = P[(size_t)n * CCODES + lane + 64 * j];

    // z row + ||z||^2
    float zv[8];
    float zn2 = 0.f;
    #pragma unroll
    for (int j = 0; j < 8; ++j) {
        zv[j] = Z[(size_t)n * DBASIS + lane + 64 * j];
        zn2 = fmaf(zv[j], zv[j], zn2);
    }
    #pragma unroll
    for (int off = 32; off; off >>= 1) zn2 += __shfl_xor(zn2, off, 64);

    // approx top-16 candidate extraction (set membership only; exactness not needed)
    int idx16[NCAND];
    #pragma unroll
    for (int t = 0; t < NCAND; ++t) {
        float bv = v[0];
        int   bj = 0;
        #pragma unroll
        for (int j = 1; j < 16; ++j)
            if (v[j] < bv) { bv = v[j]; bj = j; }
        int bcn = lane + 64 * bj;
        #pragma unroll
        for (int off = 32; off; off >>= 1) {
            const float ov = __shfl_xor(bv, off, 64);
            const int   oc = __shfl_xor(bcn, off, 64);
            if (ov < bv || (ov == bv && oc < bcn)) { bv = ov; bcn = oc; }
        }
        idx16[t] = bcn;
        const int kl = bcn & 63, kj = bcn >> 6;
        #pragma unroll
        for (int j = 0; j < 16; ++j)
            if (lane == kl && j == kj) v[j] = FLT_MAX;
    }

    // exact f32 refine of 16 candidates (embed rows are L2/L3-resident)
    float d16[NCAND];
    #pragma unroll
    for (int t = 0; t < NCAND; ++t) {
        const int c = idx16[t];                         // wave-uniform
        const float* er = embed + (size_t)c * DBASIS;
        float dot = 0.f;
        #pragma unroll
        for (int j = 0; j < 8; ++j) dot = fmaf(zv[j], er[lane + 64 * j], dot);
        #pragma unroll
        for (int off = 32; off; off >>= 1) dot += __shfl_xor(dot, off, 64);
        const float d2 = zn2 + en2[c] - 2.f * dot;
        d16[t] = sqrtf(fmaxf(d2, 0.f));
    }

    // exact top-8 among the 16 (ascending dist, lower-index tie-break = lax.top_k)
    float dist[KTOP];
    int   idx[KTOP];
    #pragma unroll
    for (int t = 0; t < KTOP; ++t) {
        float bd = d16[0];
        int   bi = idx16[0];
        int   bu = 0;
        #pragma unroll
        for (int u = 1; u < NCAND; ++u) {
            const bool better = (d16[u] < bd) || (d16[u] == bd && idx16[u] < bi);
            if (better) { bd = d16[u]; bi = idx16[u]; bu = u; }
        }
        dist[t] = bd; idx[t] = bi;
        #pragma unroll
        for (int u = 0; u < NCAND; ++u)
            if (u == bu) d16[u] = FLT_MAX;
    }

    // softmax over -dist/TEMP
    float wgt[KTOP];
    float s = 0.f;
    #pragma unroll
    for (int t = 0; t < KTOP; ++t) {
        wgt[t] = expf((dist[0] - dist[t]) * (1.0f / TEMP_F));
        s += wgt[t];
    }
    const float inv_s = 1.f / s;
    #pragma unroll
    for (int t = 0; t < KTOP; ++t) wgt[t] *= inv_s;

    // q row + fused vq partial
    float lloss = 0.f;
    #pragma unroll
    for (int j = 0; j < 8; ++j) {
        const int d = lane + 64 * j;
        float acc = 0.f;
        #pragma unroll
        for (int t = 0; t < KTOP; ++t)
            acc = fmaf(wgt[t], embed[(size_t)idx[t] * DBASIS + d], acc);
        q_out[(size_t)n * DBASIS + d] = acc;
        const float df = zv[j] - acc;
        lloss = fmaf(df, df, lloss);
    }
    #pragma unroll
    for (int off = 32; off; off >>= 1) lloss += __shfl_xor(lloss, off, 64);

    __shared__ float ls[4];
    if (lane == 0) ls[w] = lloss;
    __syncthreads();
    if (tid == 0) atomicAdd(vq_accum, ls[0] + ls[1] + ls[2] + ls[3]);

    #pragma unroll
    for (int t = 0; t < KTOP; ++t)
        if (lane == t) atomicAdd(usage + idx[t], wgt[t] * (1.0f / (float)NROWS));

    if (lane == 0) idx_out[n] = (float)idx[0];
}

// ---------------------------------------------------------------------------
// Finalize: entropy over usage; vq_loss mean
// ---------------------------------------------------------------------------
__global__ __launch_bounds__(256) void k_final(const float* __restrict__ usage,
                                               const float* __restrict__ vq_accum,
                                               float* __restrict__ out_scalars) {
    __shared__ float red[256];
    float s = 0.f;
    for (int c = threadIdx.x; c < CCODES; c += 256) {
        const float u = usage[c];
        s += u * logf(u + 1e-8f);
    }
    red[threadIdx.x] = s;
    __syncthreads();
    for (int st = 128; st; st >>= 1) {
        if (threadIdx.x < st) red[threadIdx.x] += red[threadIdx.x + st];
        __syncthreads();
    }
    if (threadIdx.x == 0) {
        out_scalars[0] = vq_accum[0] * (1.0f / ((float)NROWS * (float)DBASIS));
        out_scalars[1] = -red[0];
    }
}

// ---------------------------------------------------------------------------
extern "C" void kernel_launch(void* const* d_in, const int* in_sizes, int n_in,
                              void* d_out, int out_size, void* d_ws, size_t ws_size,
                              hipStream_t stream) {
    const float* slot  = (const float*)d_in[0];   // [16384][256]
    const float* projW = (const float*)d_in[1];   // [256][512]
    const float* projb = (const float*)d_in[2];   // [512]
    const float* embed = (const float*)d_in[3];   // [1024][512]

    float* out  = (float*)d_out;
    float* q    = out;                            // 16384*512
    float* idxo = out + (size_t)NROWS * DBASIS;   // 16384
    float* scal = idxo + NROWS;                   // 2

    // workspace layout (bytes): Z 32MB | P 64MB | Zh 16MB | Zl 16MB |
    //                           Eh 1MB | El 1MB | en2 4KB | usage 4KB | vq 4B
    char* wsb = (char*)d_ws;
    float*          Z     = (float*)wsb;                                  wsb += (size_t)NROWS * DBASIS * 4;
    float*          P     = (float*)wsb;                                  wsb += (size_t)NROWS * CCODES * 4;
    unsigned short* Zh    = (unsigned short*)wsb;                         wsb += (size_t)NROWS * DBASIS * 2;
    unsigned short* Zl    = (unsigned short*)wsb;                         wsb += (size_t)NROWS * DBASIS * 2;
    unsigned short* Eh    = (unsigned short*)wsb;                         wsb += (size_t)CCODES * DBASIS * 2;
    unsigned short* El    = (unsigned short*)wsb;                         wsb += (size_t)CCODES * DBASIS * 2;
    float*          en2   = (float*)wsb;                                  wsb += CCODES * 4;
    float*          usage = (float*)wsb;                                  wsb += CCODES * 4;
    float*          vq    = (float*)wsb;

    k_prep<<<dim3(CCODES / 256), dim3(256), 0, stream>>>(embed, Eh, El, en2, usage, vq);
    k_gemm_z<<<dim3(NROWS / 128, DBASIS / 128), dim3(256), 0, stream>>>(slot, projW, projb, Z, Zh, Zl);
    k_gemm_p<<<dim3(NROWS / 128, CCODES / 128), dim3(256), 0, stream>>>(Zh, Zl, Eh, El, en2, P);
    k_topk<<<dim3(NROWS / 4), dim3(256), 0, stream>>>(P, Z, embed, en2, q, idxo, usage, vq);
    k_final<<<dim3(1), dim3(256), 0, stream>>>(usage, vq, scal);
}

// Round 4
// 380.628 us; speedup vs baseline: 1.0802x; 1.0802x over previous
//
#include <hip/hip_runtime.h>
#include <math.h>
#include <float.h>

// Problem constants (from reference setup_inputs)
#define NROWS  16384   // B*K = 256*64
#define DIN    256
#define DBASIS 512
#define CCODES 1024
#define KTOP   8
#define TEMP_F 0.1f

typedef __attribute__((ext_vector_type(8))) short short8v;  // 8 x bf16 (4 VGPRs)
typedef __attribute__((ext_vector_type(4))) float f32x4;    // MFMA C/D

__device__ __forceinline__ unsigned short bf16_rne(float f) {
    unsigned int u = __float_as_uint(f);
    u += 0x7FFFu + ((u >> 16) & 1u);
    return (unsigned short)(u >> 16);
}
__device__ __forceinline__ float bf16_to_f32(unsigned short h) {
    return __uint_as_float(((unsigned int)h) << 16);
}
// selection key: d2 (non-neg f32, uint-order-isomorphic) with low 10 mantissa
// bits replaced by the code index. 0.0625 granularity at d2~680 — far below
// the ~2.5 d2 gap at ranks 8..16, so candidate-set membership is safe.
__device__ __forceinline__ unsigned packkey(float p, float zn2, unsigned cidx) {
    const float d2 = fmaxf(p + zn2, 0.f);
    return (__float_as_uint(d2) & 0xFFFFFC00u) | cidx;
}

// ---------------------------------------------------------------------------
// Prep: embed row norms, Eh/El bf16 split, zero usage + vq accumulator
// ---------------------------------------------------------------------------
__global__ __launch_bounds__(256) void k_prep(const float* __restrict__ embed,
                                              unsigned short* __restrict__ Eh,
                                              unsigned short* __restrict__ El,
                                              float* __restrict__ en2,
                                              float* __restrict__ usage,
                                              float* __restrict__ vq_accum) {
    const int c = blockIdx.x * 256 + threadIdx.x;   // grid exactly CCODES threads
    const float4* row = (const float4*)(embed + (size_t)c * DBASIS);
    ushort4* ehr = (ushort4*)(Eh + (size_t)c * DBASIS);
    ushort4* elr = (ushort4*)(El + (size_t)c * DBASIS);
    float s = 0.f;
    #pragma unroll 4
    for (int j = 0; j < DBASIS / 4; ++j) {
        const float4 v = row[j];
        s += v.x * v.x + v.y * v.y + v.z * v.z + v.w * v.w;
        ushort4 h, l;
        h.x = bf16_rne(v.x); l.x = bf16_rne(v.x - bf16_to_f32(h.x));
        h.y = bf16_rne(v.y); l.y = bf16_rne(v.y - bf16_to_f32(h.y));
        h.z = bf16_rne(v.z); l.z = bf16_rne(v.z - bf16_to_f32(h.z));
        h.w = bf16_rne(v.w); l.w = bf16_rne(v.w - bf16_to_f32(h.w));
        ehr[j] = h; elr[j] = l;
    }
    en2[c] = s;
    usage[c] = 0.f;
    if (c == 0) vq_accum[0] = 0.f;
}

// ---------------------------------------------------------------------------
// Prep: slot_features bf16 hi/lo split (grid covers exactly 1,048,576 float4)
// ---------------------------------------------------------------------------
__global__ __launch_bounds__(256) void k_prep_slot(const float* __restrict__ in,
                                                   unsigned short* __restrict__ Sh,
                                                   unsigned short* __restrict__ Sl) {
    const int i = blockIdx.x * 256 + threadIdx.x;
    const float4 v = ((const float4*)in)[i];
    ushort4 h, l;
    h.x = bf16_rne(v.x); l.x = bf16_rne(v.x - bf16_to_f32(h.x));
    h.y = bf16_rne(v.y); l.y = bf16_rne(v.y - bf16_to_f32(h.y));
    h.z = bf16_rne(v.z); l.z = bf16_rne(v.z - bf16_to_f32(h.z));
    h.w = bf16_rne(v.w); l.w = bf16_rne(v.w - bf16_to_f32(h.w));
    ((ushort4*)Sh)[i] = h;
    ((ushort4*)Sl)[i] = l;
}

// ---------------------------------------------------------------------------
// Prep: transpose projW [256][512] -> Wt [512][256] with bf16 hi/lo split
// ---------------------------------------------------------------------------
__global__ __launch_bounds__(256) void k_prep_w(const float* __restrict__ W,
                                                unsigned short* __restrict__ Wh,
                                                unsigned short* __restrict__ Wl) {
    __shared__ float tile[32][33];
    const int k0 = blockIdx.x * 32;   // 8 blocks over K=256
    const int n0 = blockIdx.y * 32;   // 16 blocks over N=512
    const int tx = threadIdx.x & 31, ty = threadIdx.x >> 5;
    #pragma unroll
    for (int i = 0; i < 32; i += 8)
        tile[ty + i][tx] = W[(size_t)(k0 + ty + i) * DBASIS + n0 + tx];
    __syncthreads();
    #pragma unroll
    for (int i = 0; i < 32; i += 8) {
        const int n = n0 + ty + i, k = k0 + tx;
        const float v = tile[tx][ty + i];
        const unsigned short h = bf16_rne(v);
        Wh[(size_t)n * DIN + k] = h;
        Wl[(size_t)n * DIN + k] = bf16_rne(v - bf16_to_f32(h));
    }
}

// ---------------------------------------------------------------------------
// GEMM 1 (MFMA bf16-split NT): Z[m][n] = sum_k slot[m][k]*Wt[n][k] + b[n]
//   = Sh.Wh + Sh.Wl + Sl.Wh.  M=16384, N=512, Keff=3*256. Structural clone of
//   k_gemm_p (HW-verified round 3). Epilogue: +bias, write Z f32 and Zh/Zl.
// ---------------------------------------------------------------------------
__global__ __launch_bounds__(256, 2) void k_gemm_z_mfma(const unsigned short* __restrict__ Sh,
                                                        const unsigned short* __restrict__ Sl,
                                                        const unsigned short* __restrict__ Wh,
                                                        const unsigned short* __restrict__ Wl,
                                                        const float* __restrict__ bias,
                                                        float* __restrict__ Z,
                                                        unsigned short* __restrict__ Zh,
                                                        unsigned short* __restrict__ Zl) {
    __shared__ __align__(16) short ldsA[4096];
    __shared__ __align__(16) short ldsB[4096];
    const int tid  = threadIdx.x;
    const int lane = tid & 63;
    const int w    = tid >> 6;
    const int wr   = w >> 1, wc = w & 1;
    const int bm   = blockIdx.x * 128;
    const int bc   = blockIdx.y * 128;

    f32x4 acc[4][4];
    #pragma unroll
    for (int i = 0; i < 4; ++i)
        #pragma unroll
        for (int j = 0; j < 4; ++j)
            acc[i][j] = (f32x4){0.f, 0.f, 0.f, 0.f};

    for (int ch = 0; ch < 24; ++ch) {
        const int term = ch >> 3;            // 0: Sh.Wh  1: Sh.Wl  2: Sl.Wh
        const int k0   = (ch & 7) * 32;
        const unsigned short* Asrc = (term == 2) ? Sl : Sh;
        const unsigned short* Bsrc = (term == 1) ? Wl : Wh;
        #pragma unroll
        for (int j = 0; j < 2; ++j) {
            const int gi = j * 256 + tid;    // granule: g = k-octet, r = row
            const int g  = gi >> 7;
            const int r  = gi & 127;
            const unsigned short* ga = Asrc + (size_t)(bm + r) * DIN + k0 + g * 8;
            const unsigned short* gb = Bsrc + (size_t)(bc + r) * DIN + k0 + g * 8;
            __builtin_amdgcn_global_load_lds((const __attribute__((address_space(1))) void*)ga,
                                             (__attribute__((address_space(3))) void*)(&ldsA[gi * 8]),
                                             16, 0, 0);
            __builtin_amdgcn_global_load_lds((const __attribute__((address_space(1))) void*)gb,
                                             (__attribute__((address_space(3))) void*)(&ldsB[gi * 8]),
                                             16, 0, 0);
        }
        __syncthreads();

        const int kg = lane >> 4;
        const int lr = lane & 15;
        short8v af[4], bf[4];
        #pragma unroll
        for (int f = 0; f < 4; ++f) {
            af[f] = *(const short8v*)&ldsA[(kg * 128 + wr * 64 + f * 16 + lr) * 8];
            bf[f] = *(const short8v*)&ldsB[(kg * 128 + wc * 64 + f * 16 + lr) * 8];
        }
        #pragma unroll
        for (int fm = 0; fm < 4; ++fm)
            #pragma unroll
            for (int fn = 0; fn < 4; ++fn)
                acc[fm][fn] = __builtin_amdgcn_mfma_f32_16x16x32_bf16(af[fm], bf[fn], acc[fm][fn], 0, 0, 0);
        __syncthreads();
    }

    #pragma unroll
    for (int fn = 0; fn < 4; ++fn) {
        const int col = bc + wc * 64 + fn * 16 + (lane & 15);
        const float bb = bias[col];
        #pragma unroll
        for (int fm = 0; fm < 4; ++fm) {
            const int row0 = bm + wr * 64 + fm * 16 + (lane >> 4) * 4;
            #pragma unroll
            for (int r = 0; r < 4; ++r) {
                const float val = acc[fm][fn][r] + bb;
                const size_t o = (size_t)(row0 + r) * DBASIS + col;
                Z[o] = val;
                const unsigned short h = bf16_rne(val);
                Zh[o] = h;
                Zl[o] = bf16_rne(val - bf16_to_f32(h));
            }
        }
    }
}

// ---------------------------------------------------------------------------
// GEMM 2 (MFMA bf16-split): Papprox[m][c] = en2[c] - 2*(Zh.Eh + Zh.El + Zl.Eh)
// Unchanged from round 3 (HW-verified PASS).
// ---------------------------------------------------------------------------
__global__ __launch_bounds__(256, 2) void k_gemm_p(const unsigned short* __restrict__ Zh,
                                                   const unsigned short* __restrict__ Zl,
                                                   const unsigned short* __restrict__ Eh,
                                                   const unsigned short* __restrict__ El,
                                                   const float* __restrict__ en2,
                                                   float* __restrict__ P) {
    __shared__ __align__(16) short ldsA[4096];
    __shared__ __align__(16) short ldsB[4096];
    const int tid  = threadIdx.x;
    const int lane = tid & 63;
    const int w    = tid >> 6;
    const int wr   = w >> 1, wc = w & 1;
    const int bm   = blockIdx.x * 128;
    const int bc   = blockIdx.y * 128;

    f32x4 acc[4][4];
    #pragma unroll
    for (int i = 0; i < 4; ++i)
        #pragma unroll
        for (int j = 0; j < 4; ++j)
            acc[i][j] = (f32x4){0.f, 0.f, 0.f, 0.f};

    for (int ch = 0; ch < 48; ++ch) {
        const int term = ch >> 4;            // 0: Zh.Eh  1: Zh.El  2: Zl.Eh
        const int k0   = (ch & 15) * 32;
        const unsigned short* Asrc = (term == 2) ? Zl : Zh;
        const unsigned short* Bsrc = (term == 1) ? El : Eh;
        #pragma unroll
        for (int j = 0; j < 2; ++j) {
            const int gi = j * 256 + tid;
            const int g  = gi >> 7;
            const int r  = gi & 127;
            const unsigned short* ga = Asrc + (size_t)(bm + r) * DBASIS + k0 + g * 8;
            const unsigned short* gb = Bsrc + (size_t)(bc + r) * DBASIS + k0 + g * 8;
            __builtin_amdgcn_global_load_lds((const __attribute__((address_space(1))) void*)ga,
                                             (__attribute__((address_space(3))) void*)(&ldsA[gi * 8]),
                                             16, 0, 0);
            __builtin_amdgcn_global_load_lds((const __attribute__((address_space(1))) void*)gb,
                                             (__attribute__((address_space(3))) void*)(&ldsB[gi * 8]),
                                             16, 0, 0);
        }
        __syncthreads();

        const int kg = lane >> 4;
        const int lr = lane & 15;
        short8v af[4], bf[4];
        #pragma unroll
        for (int f = 0; f < 4; ++f) {
            af[f] = *(const short8v*)&ldsA[(kg * 128 + wr * 64 + f * 16 + lr) * 8];
            bf[f] = *(const short8v*)&ldsB[(kg * 128 + wc * 64 + f * 16 + lr) * 8];
        }
        #pragma unroll
        for (int fm = 0; fm < 4; ++fm)
            #pragma unroll
            for (int fn = 0; fn < 4; ++fn)
                acc[fm][fn] = __builtin_amdgcn_mfma_f32_16x16x32_bf16(af[fm], bf[fn], acc[fm][fn], 0, 0, 0);
        __syncthreads();
    }

    #pragma unroll
    for (int fn = 0; fn < 4; ++fn) {
        const int col = bc + wc * 64 + fn * 16 + (lane & 15);
        const float e2 = en2[col];
        #pragma unroll
        for (int fm = 0; fm < 4; ++fm) {
            const int row0 = bm + wr * 64 + fm * 16 + (lane >> 4) * 4;
            #pragma unroll
            for (int r = 0; r < 4; ++r)
                P[(size_t)(row0 + r) * CCODES + col] = e2 - 2.f * acc[fm][fn][r];
        }
    }
}

// ---------------------------------------------------------------------------
// Top-k v2: threshold candidate select + exact refine + top-8.
// One wave per row, 4 rows per block.
//   T = 16th-smallest lane-min of packed keys  =>  count(keys<=T) >= 16 and
//   T >= global 16th-smallest key, so the exact top-8 (key-rank <~10) is
//   always in the candidate set. Candidates compacted to LDS, refined in
//   exact f32, then 8 butterfly argmins (dist asc, index tie-break).
// ---------------------------------------------------------------------------
__global__ __launch_bounds__(256) void k_topk(const float* __restrict__ P,
                                              const float* __restrict__ Z,
                                              const float* __restrict__ embed,
                                              const float* __restrict__ en2,
                                              float* __restrict__ q_out,
                                              float* __restrict__ idx_out,
                                              float* __restrict__ usage,
                                              float* __restrict__ vq_accum) {
    const int tid  = threadIdx.x;
    const int lane = tid & 63;
    const int w    = tid >> 6;
    const int n    = blockIdx.x * 4 + w;

    __shared__ int   cand_lds[4][64];
    __shared__ float ls[4];

    // z row + ||z||^2
    float zv[8];
    float zn2 = 0.f;
    #pragma unroll
    for (int j = 0; j < 8; ++j) {
        zv[j] = Z[(size_t)n * DBASIS + lane + 64 * j];
        zn2 = fmaf(zv[j], zv[j], zn2);
    }
    #pragma unroll
    for (int off = 32; off; off >>= 1) zn2 += __shfl_xor(zn2, off, 64);

    // P row: 16 contiguous values per lane (4 x dwordx4)
    const float4* prow = (const float4*)(P + (size_t)n * CCODES + lane * 16);
    const unsigned cbase = (unsigned)(lane * 16);
    unsigned key[16];
    #pragma unroll
    for (int j = 0; j < 4; ++j) {
        const float4 v = prow[j];
        key[4 * j + 0] = packkey(v.x, zn2, cbase + 4 * j + 0);
        key[4 * j + 1] = packkey(v.y, zn2, cbase + 4 * j + 1);
        key[4 * j + 2] = packkey(v.z, zn2, cbase + 4 * j + 2);
        key[4 * j + 3] = packkey(v.w, zn2, cbase + 4 * j + 3);
    }

    // lane-local min key
    unsigned kmin = key[0];
    #pragma unroll
    for (int t = 1; t < 16; ++t) kmin = (key[t] < kmin) ? key[t] : kmin;

    // T = 16th smallest lane-min (uniform binary search on uint keys)
    unsigned lo = 0u, hi = 0xFFFFFFFFu;
    while (lo < hi) {
        const unsigned mid = lo + ((hi - lo) >> 1);
        const unsigned long long mk = __ballot(kmin <= mid);
        if (__popcll(mk) >= 16) hi = mid; else lo = mid + 1;
    }
    const unsigned T = lo;

    // compact candidates (key <= T) into LDS
    int* clist = cand_lds[w];
    int base = 0;
    #pragma unroll
    for (int t = 0; t < 16; ++t) {
        const bool pred = (key[t] <= T);
        const unsigned long long mk = __ballot(pred);
        const int pos = base + __popcll(mk & ((1ull << lane) - 1ull));
        if (pred && pos < 64) clist[pos] = (int)(cbase + t);
        base += __popcll(mk);
    }
    const int m = base < 64 ? base : 64;

    // exact f32 refine (wave-serial over candidates, lane-parallel over dims);
    // candidate t's (dist, idx) parked on lane t
    float mydist = FLT_MAX;
    int   myidx  = 0x7FFFFFFF;
    for (int t = 0; t < m; ++t) {
        const int c = clist[t];                       // wave-uniform broadcast
        const float* er = embed + (size_t)c * DBASIS;
        float dot = 0.f;
        #pragma unroll
        for (int j = 0; j < 8; ++j) dot = fmaf(zv[j], er[lane + 64 * j], dot);
        #pragma unroll
        for (int off = 32; off; off >>= 1) dot += __shfl_xor(dot, off, 64);
        const float d = sqrtf(fmaxf(zn2 + en2[c] - 2.f * dot, 0.f));
        if (lane == t) { mydist = d; myidx = c; }
    }

    // exact top-8: butterfly argmin x8 (dist asc, lower code index on ties)
    float dist[KTOP];
    int   idx[KTOP];
    #pragma unroll
    for (int p = 0; p < KTOP; ++p) {
        float bv = mydist;
        int   bi = myidx;
        #pragma unroll
        for (int off = 32; off; off >>= 1) {
            const float ov = __shfl_xor(bv, off, 64);
            const int   oi = __shfl_xor(bi, off, 64);
            if (ov < bv || (ov == bv && oi < bi)) { bv = ov; bi = oi; }
        }
        dist[p] = bv; idx[p] = bi;
        if (myidx == bi) { mydist = FLT_MAX; myidx = 0x7FFFFFFF; }
    }

    // softmax over -dist/TEMP (dist[0] is the min -> exponents <= 0)
    float wgt[KTOP];
    float s = 0.f;
    #pragma unroll
    for (int t = 0; t < KTOP; ++t) {
        wgt[t] = expf((dist[0] - dist[t]) * (1.0f / TEMP_F));
        s += wgt[t];
    }
    const float inv_s = 1.f / s;
    #pragma unroll
    for (int t = 0; t < KTOP; ++t) wgt[t] *= inv_s;

    // q row + fused vq partial
    float lloss = 0.f;
    #pragma unroll
    for (int j = 0; j < 8; ++j) {
        const int d = lane + 64 * j;
        float acc = 0.f;
        #pragma unroll
        for (int t = 0; t < KTOP; ++t)
            acc = fmaf(wgt[t], embed[(size_t)idx[t] * DBASIS + d], acc);
        q_out[(size_t)n * DBASIS + d] = acc;
        const float df = zv[j] - acc;
        lloss = fmaf(df, df, lloss);
    }
    #pragma unroll
    for (int off = 32; off; off >>= 1) lloss += __shfl_xor(lloss, off, 64);

    if (lane == 0) ls[w] = lloss;
    __syncthreads();
    if (tid == 0) atomicAdd(vq_accum, ls[0] + ls[1] + ls[2] + ls[3]);

    #pragma unroll
    for (int t = 0; t < KTOP; ++t)
        if (lane == t) atomicAdd(usage + idx[t], wgt[t] * (1.0f / (float)NROWS));

    if (lane == 0) idx_out[n] = (float)idx[0];
}

// ---------------------------------------------------------------------------
// Finalize: entropy over usage; vq_loss mean
// ---------------------------------------------------------------------------
__global__ __launch_bounds__(256) void k_final(const float* __restrict__ usage,
                                               const float* __restrict__ vq_accum,
                                               float* __restrict__ out_scalars) {
    __shared__ float red[256];
    float s = 0.f;
    for (int c = threadIdx.x; c < CCODES; c += 256) {
        const float u = usage[c];
        s += u * logf(u + 1e-8f);
    }
    red[threadIdx.x] = s;
    __syncthreads();
    for (int st = 128; st; st >>= 1) {
        if (threadIdx.x < st) red[threadIdx.x] += red[threadIdx.x + st];
        __syncthreads();
    }
    if (threadIdx.x == 0) {
        out_scalars[0] = vq_accum[0] * (1.0f / ((float)NROWS * (float)DBASIS));
        out_scalars[1] = -red[0];
    }
}

// ---------------------------------------------------------------------------
extern "C" void kernel_launch(void* const* d_in, const int* in_sizes, int n_in,
                              void* d_out, int out_size, void* d_ws, size_t ws_size,
                              hipStream_t stream) {
    const float* slot  = (const float*)d_in[0];   // [16384][256]
    const float* projW = (const float*)d_in[1];   // [256][512]
    const float* projb = (const float*)d_in[2];   // [512]
    const float* embed = (const float*)d_in[3];   // [1024][512]

    float* out  = (float*)d_out;
    float* q    = out;                            // 16384*512
    float* idxo = out + (size_t)NROWS * DBASIS;   // 16384
    float* scal = idxo + NROWS;                   // 2

    // workspace layout
    char* wsb = (char*)d_ws;
    float*          Z     = (float*)wsb;          wsb += (size_t)NROWS * DBASIS * 4;   // 32 MB
    float*          P     = (float*)wsb;          wsb += (size_t)NROWS * CCODES * 4;   // 64 MB
    unsigned short* Zh    = (unsigned short*)wsb; wsb += (size_t)NROWS * DBASIS * 2;   // 16 MB
    unsigned short* Zl    = (unsigned short*)wsb; wsb += (size_t)NROWS * DBASIS * 2;   // 16 MB
    unsigned short* Eh    = (unsigned short*)wsb; wsb += (size_t)CCODES * DBASIS * 2;  // 1 MB
    unsigned short* El    = (unsigned short*)wsb; wsb += (size_t)CCODES * DBASIS * 2;  // 1 MB
    unsigned short* Sh    = (unsigned short*)wsb; wsb += (size_t)NROWS * DIN * 2;      // 8 MB
    unsigned short* Sl    = (unsigned short*)wsb; wsb += (size_t)NROWS * DIN * 2;      // 8 MB
    unsigned short* Wh    = (unsigned short*)wsb; wsb += (size_t)DBASIS * DIN * 2;     // 256 KB
    unsigned short* Wl    = (unsigned short*)wsb; wsb += (size_t)DBASIS * DIN * 2;     // 256 KB
    float*          en2   = (float*)wsb;          wsb += CCODES * 4;
    float*          usage = (float*)wsb;          wsb += CCODES * 4;
    float*          vq    = (float*)wsb;

    k_prep<<<dim3(CCODES / 256), dim3(256), 0, stream>>>(embed, Eh, El, en2, usage, vq);
    k_prep_slot<<<dim3(NROWS * DIN / 4 / 256), dim3(256), 0, stream>>>(slot, Sh, Sl);
    k_prep_w<<<dim3(DIN / 32, DBASIS / 32), dim3(256), 0, stream>>>(projW, Wh, Wl);
    k_gemm_z_mfma<<<dim3(NROWS / 128, DBASIS / 128), dim3(256), 0, stream>>>(Sh, Sl, Wh, Wl, projb, Z, Zh, Zl);
    k_gemm_p<<<dim3(NROWS / 128, CCODES / 128), dim3(256), 0, stream>>>(Zh, Zl, Eh, El, en2, P);
    k_topk<<<dim3(NROWS / 4), dim3(256), 0, stream>>>(P, Z, embed, en2, q, idxo, usage, vq);
    k_final<<<dim3(1), dim3(256), 0, stream>>>(usage, vq, scal);
}

// Round 7
// 371.914 us; speedup vs baseline: 1.1055x; 1.0234x over previous
//
#include <hip/hip_runtime.h>
#include <math.h>
#include <float.h>

// Problem constants (from reference setup_inputs)
#define NROWS  16384   // B*K = 256*64
#define DIN    256
#define DBASIS 512
#define CCODES 1024
#define KTOP   8
#define TEMP_F 0.1f

typedef __attribute__((ext_vector_type(8))) short short8v;  // 8 x bf16 (4 VGPRs)
typedef __attribute__((ext_vector_type(4))) float f32x4;    // MFMA C/D

__device__ __forceinline__ unsigned short bf16_rne(float f) {
    unsigned int u = __float_as_uint(f);
    u += 0x7FFFu + ((u >> 16) & 1u);
    return (unsigned short)(u >> 16);
}
__device__ __forceinline__ float bf16_to_f32(unsigned short h) {
    return __uint_as_float(((unsigned int)h) << 16);
}
// selection key: d2 (non-neg f32, uint-order-isomorphic) with low 10 mantissa
// bits replaced by the code index.
__device__ __forceinline__ unsigned packkey(float p, float zn2, unsigned cidx) {
    const float d2 = fmaxf(p + zn2, 0.f);
    return (__float_as_uint(d2) & 0xFFFFFC00u) | cidx;
}

#define GLOAD16(gsrc, ldst) \
    __builtin_amdgcn_global_load_lds((const __attribute__((address_space(1))) void*)(gsrc), \
                                     (__attribute__((address_space(3))) void*)(ldst), 16, 0, 0)

// ---------------------------------------------------------------------------
// Prep: embed row norms, Eh/El bf16 split, zero usage + vq accumulator
// ---------------------------------------------------------------------------
__global__ __launch_bounds__(256) void k_prep(const float* __restrict__ embed,
                                              unsigned short* __restrict__ Eh,
                                              unsigned short* __restrict__ El,
                                              float* __restrict__ en2,
                                              float* __restrict__ usage,
                                              float* __restrict__ vq_accum) {
    const int c = blockIdx.x * 256 + threadIdx.x;
    const float4* row = (const float4*)(embed + (size_t)c * DBASIS);
    ushort4* ehr = (ushort4*)(Eh + (size_t)c * DBASIS);
    ushort4* elr = (ushort4*)(El + (size_t)c * DBASIS);
    float s = 0.f;
    #pragma unroll 4
    for (int j = 0; j < DBASIS / 4; ++j) {
        const float4 v = row[j];
        s += v.x * v.x + v.y * v.y + v.z * v.z + v.w * v.w;
        ushort4 h, l;
        h.x = bf16_rne(v.x); l.x = bf16_rne(v.x - bf16_to_f32(h.x));
        h.y = bf16_rne(v.y); l.y = bf16_rne(v.y - bf16_to_f32(h.y));
        h.z = bf16_rne(v.z); l.z = bf16_rne(v.z - bf16_to_f32(h.z));
        h.w = bf16_rne(v.w); l.w = bf16_rne(v.w - bf16_to_f32(h.w));
        ehr[j] = h; elr[j] = l;
    }
    en2[c] = s;
    usage[c] = 0.f;
    if (c == 0) vq_accum[0] = 0.f;
}

// ---------------------------------------------------------------------------
// GEMM 1 (NN, f32 VALU — EXACT, HW-verified round 3): Z = slot @ W + b.
// M=16384, N=512, K=256. 128x128 tile, BK=16, 8x8 micro-tile in quadrants.
// Z must be f32-exact: the refine/top-1 path orders near-ties at the ~1e-5
// level; bf16-split Z (~1e-4) flips indices (round-5 failure).
// Epilogue also emits the bf16 hi/lo split of Z for the MFMA distance GEMM.
// ---------------------------------------------------------------------------
__global__ __launch_bounds__(256, 2) void k_gemm_z(const float* __restrict__ A,
                                                   const float* __restrict__ Bm,
                                                   const float* __restrict__ bias,
                                                   float* __restrict__ Z,
                                                   unsigned short* __restrict__ Zh,
                                                   unsigned short* __restrict__ Zl) {
    __shared__ float As[16][132];
    __shared__ float Bs[16][132];
    const int tid = threadIdx.x;
    const int bm = blockIdx.x * 128;
    const int bn = blockIdx.y * 128;
    const int tx = tid & 15, ty = tid >> 4;
    float acc[2][2][4][4] = {};

    for (int k0 = 0; k0 < DIN; k0 += 16) {
        #pragma unroll
        for (int it = 0; it < 2; ++it) {
            const int r  = (tid >> 2) + it * 64;
            const int c4 = (tid & 3) * 4;
            const float4 a = *(const float4*)(A + (size_t)(bm + r) * DIN + k0 + c4);
            As[c4 + 0][r] = a.x; As[c4 + 1][r] = a.y;
            As[c4 + 2][r] = a.z; As[c4 + 3][r] = a.w;
        }
        {
            const int r  = tid >> 4;
            const int c8 = (tid & 15) * 8;
            const float4 b0 = *(const float4*)(Bm + (size_t)(k0 + r) * DBASIS + bn + c8);
            const float4 b1 = *(const float4*)(Bm + (size_t)(k0 + r) * DBASIS + bn + c8 + 4);
            *(float4*)&Bs[r][c8]     = b0;
            *(float4*)&Bs[r][c8 + 4] = b1;
        }
        __syncthreads();
        #pragma unroll
        for (int kk = 0; kk < 16; ++kk) {
            const float4 a0 = *(const float4*)&As[kk][ty * 4];
            const float4 a1 = *(const float4*)&As[kk][64 + ty * 4];
            const float4 b0 = *(const float4*)&Bs[kk][tx * 4];
            const float4 b1 = *(const float4*)&Bs[kk][64 + tx * 4];
            const float av[2][4] = {{a0.x, a0.y, a0.z, a0.w}, {a1.x, a1.y, a1.z, a1.w}};
            const float bv[2][4] = {{b0.x, b0.y, b0.z, b0.w}, {b1.x, b1.y, b1.z, b1.w}};
            #pragma unroll
            for (int qi = 0; qi < 2; ++qi)
                #pragma unroll
                for (int qj = 0; qj < 2; ++qj)
                    #pragma unroll
                    for (int i = 0; i < 4; ++i)
                        #pragma unroll
                        for (int j = 0; j < 4; ++j)
                            acc[qi][qj][i][j] = fmaf(av[qi][i], bv[qj][j], acc[qi][qj][i][j]);
        }
        __syncthreads();
    }
    #pragma unroll
    for (int qj = 0; qj < 2; ++qj) {
        const int colb = bn + qj * 64 + tx * 4;
        const float4 bv = *(const float4*)(bias + colb);
        const float bb[4] = {bv.x, bv.y, bv.z, bv.w};
        #pragma unroll
        for (int qi = 0; qi < 2; ++qi)
            #pragma unroll
            for (int i = 0; i < 4; ++i) {
                const int row = bm + qi * 64 + ty * 4 + i;
                float4 o;
                o.x = acc[qi][qj][i][0] + bb[0];
                o.y = acc[qi][qj][i][1] + bb[1];
                o.z = acc[qi][qj][i][2] + bb[2];
                o.w = acc[qi][qj][i][3] + bb[3];
                *(float4*)(Z + (size_t)row * DBASIS + colb) = o;
                ushort4 h, l;
                h.x = bf16_rne(o.x); l.x = bf16_rne(o.x - bf16_to_f32(h.x));
                h.y = bf16_rne(o.y); l.y = bf16_rne(o.y - bf16_to_f32(h.y));
                h.z = bf16_rne(o.z); l.z = bf16_rne(o.z - bf16_to_f32(h.z));
                h.w = bf16_rne(o.w); l.w = bf16_rne(o.w - bf16_to_f32(h.w));
                *(ushort4*)(Zh + (size_t)row * DBASIS + colb) = h;
                *(ushort4*)(Zl + (size_t)row * DBASIS + colb) = l;
            }
    }
}

// ---------------------------------------------------------------------------
// GEMM 2 (MFMA bf16-split NT): Papprox = en2[c] - 2*(Zh.Eh + Zh.El + Zl.Eh)
// M=16384, N=1024, K=512. 128x128 tile, 4 waves 2x2. Double-buffered 4-tile
// staging (Zh,Zl,Eh,El per K=32 step), 48 MFMA/phase, 16 phases.
// Functionally verified round 5 (q/candidate sets correct).
// ---------------------------------------------------------------------------
__global__ __launch_bounds__(256, 2) void k_gemm_p(const unsigned short* __restrict__ Zh,
                                                   const unsigned short* __restrict__ Zl,
                                                   const unsigned short* __restrict__ Eh,
                                                   const unsigned short* __restrict__ El,
                                                   const float* __restrict__ en2,
                                                   float* __restrict__ P) {
    __shared__ __align__(16) short lds[2][4][4096];   // 64 KB: [buf][Ah,Al,Bh,Bl]
    const int tid  = threadIdx.x;
    const int lane = tid & 63;
    const int w    = tid >> 6;
    const int wr   = w >> 1, wc = w & 1;
    const int bm   = blockIdx.y * 128;
    const int bc   = blockIdx.x * 128;
    const int kg   = lane >> 4;
    const int lr   = lane & 15;

    f32x4 acc[4][4];
    #pragma unroll
    for (int i = 0; i < 4; ++i)
        #pragma unroll
        for (int j = 0; j < 4; ++j)
            acc[i][j] = (f32x4){0.f, 0.f, 0.f, 0.f};

#define STAGE_P(BUF, PH) do {                                                  \
        const int k0_ = (PH) * 32;                                             \
        _Pragma("unroll")                                                      \
        for (int j_ = 0; j_ < 2; ++j_) {                                       \
            const int gi_ = j_ * 256 + tid;                                    \
            const int g_  = gi_ >> 7, r_ = gi_ & 127;                          \
            const size_t ao_ = (size_t)(bm + r_) * DBASIS + k0_ + g_ * 8;      \
            const size_t bo_ = (size_t)(bc + r_) * DBASIS + k0_ + g_ * 8;      \
            GLOAD16(Zh + ao_, &lds[BUF][0][gi_ * 8]);                          \
            GLOAD16(Zl + ao_, &lds[BUF][1][gi_ * 8]);                          \
            GLOAD16(Eh + bo_, &lds[BUF][2][gi_ * 8]);                          \
            GLOAD16(El + bo_, &lds[BUF][3][gi_ * 8]);                          \
        }                                                                      \
    } while (0)

#define COMPUTE_P(BUF) do {                                                    \
        short8v afh[4], afl[4], bfh[4], bfl[4];                                \
        _Pragma("unroll")                                                      \
        for (int f = 0; f < 4; ++f) {                                          \
            const int ai = (kg * 128 + wr * 64 + f * 16 + lr) * 8;             \
            const int bi = (kg * 128 + wc * 64 + f * 16 + lr) * 8;             \
            afh[f] = *(const short8v*)&lds[BUF][0][ai];                        \
            afl[f] = *(const short8v*)&lds[BUF][1][ai];                        \
            bfh[f] = *(const short8v*)&lds[BUF][2][bi];                        \
            bfl[f] = *(const short8v*)&lds[BUF][3][bi];                        \
        }                                                                      \
        _Pragma("unroll")                                                      \
        for (int fm = 0; fm < 4; ++fm)                                         \
            _Pragma("unroll")                                                  \
            for (int fn = 0; fn < 4; ++fn) {                                   \
                acc[fm][fn] = __builtin_amdgcn_mfma_f32_16x16x32_bf16(afh[fm], bfh[fn], acc[fm][fn], 0, 0, 0); \
                acc[fm][fn] = __builtin_amdgcn_mfma_f32_16x16x32_bf16(afh[fm], bfl[fn], acc[fm][fn], 0, 0, 0); \
                acc[fm][fn] = __builtin_amdgcn_mfma_f32_16x16x32_bf16(afl[fm], bfh[fn], acc[fm][fn], 0, 0, 0); \
            }                                                                  \
    } while (0)

    STAGE_P(0, 0);
    __syncthreads();
    int cur = 0;
    for (int ph = 0; ph < 15; ++ph) {
        STAGE_P(cur ^ 1, ph + 1);
        COMPUTE_P(cur);
        __syncthreads();
        cur ^= 1;
    }
    COMPUTE_P(cur);

    #pragma unroll
    for (int fn = 0; fn < 4; ++fn) {
        const int col = bc + wc * 64 + fn * 16 + lr;
        const float e2 = en2[col];
        #pragma unroll
        for (int fm = 0; fm < 4; ++fm) {
            const int row0 = bm + wr * 64 + fm * 16 + (lane >> 4) * 4;
            #pragma unroll
            for (int r = 0; r < 4; ++r)
                P[(size_t)(row0 + r) * CCODES + col] = e2 - 2.f * acc[fm][fn][r];
        }
    }
#undef STAGE_P
#undef COMPUTE_P
}

// ---------------------------------------------------------------------------
// Top-k: threshold candidate select + exact f32 refine + top-8 (HW-verified
// rounds 4-5). One wave per row, 4 rows per block.
// ---------------------------------------------------------------------------
__global__ __launch_bounds__(256) void k_topk(const float* __restrict__ P,
                                              const float* __restrict__ Z,
                                              const float* __restrict__ embed,
                                              const float* __restrict__ en2,
                                              float* __restrict__ q_out,
                                              float* __restrict__ idx_out,
                                              float* __restrict__ usage,
                                              float* __restrict__ vq_accum) {
    const int tid  = threadIdx.x;
    const int lane = tid & 63;
    const int w    = tid >> 6;
    const int n    = blockIdx.x * 4 + w;

    __shared__ int   cand_lds[4][64];
    __shared__ float ls[4];

    float zv[8];
    float zn2 = 0.f;
    #pragma unroll
    for (int j = 0; j < 8; ++j) {
        zv[j] = Z[(size_t)n * DBASIS + lane + 64 * j];
        zn2 = fmaf(zv[j], zv[j], zn2);
    }
    #pragma unroll
    for (int off = 32; off; off >>= 1) zn2 += __shfl_xor(zn2, off, 64);

    const float4* prow = (const float4*)(P + (size_t)n * CCODES + lane * 16);
    const unsigned cbase = (unsigned)(lane * 16);
    unsigned key[16];
    #pragma unroll
    for (int j = 0; j < 4; ++j) {
        const float4 v = prow[j];
        key[4 * j + 0] = packkey(v.x, zn2, cbase + 4 * j + 0);
        key[4 * j + 1] = packkey(v.y, zn2, cbase + 4 * j + 1);
        key[4 * j + 2] = packkey(v.z, zn2, cbase + 4 * j + 2);
        key[4 * j + 3] = packkey(v.w, zn2, cbase + 4 * j + 3);
    }

    unsigned kmin = key[0];
    #pragma unroll
    for (int t = 1; t < 16; ++t) kmin = (key[t] < kmin) ? key[t] : kmin;

    unsigned lo = 0u, hi = 0xFFFFFFFFu;
    while (lo < hi) {
        const unsigned mid = lo + ((hi - lo) >> 1);
        const unsigned long long mk = __ballot(kmin <= mid);
        if (__popcll(mk) >= 16) hi = mid; else lo = mid + 1;
    }
    const unsigned T = lo;

    int* clist = cand_lds[w];
    int base = 0;
    #pragma unroll
    for (int t = 0; t < 16; ++t) {
        const bool pred = (key[t] <= T);
        const unsigned long long mk = __ballot(pred);
        const int pos = base + __popcll(mk & ((1ull << lane) - 1ull));
        if (pred && pos < 64) clist[pos] = (int)(cbase + t);
        base += __popcll(mk);
    }
    const int m = base < 64 ? base : 64;

    float mydist = FLT_MAX;
    int   myidx  = 0x7FFFFFFF;
    for (int t = 0; t < m; ++t) {
        const int c = clist[t];
        const float* er = embed + (size_t)c * DBASIS;
        float dot = 0.f;
        #pragma unroll
        for (int j = 0; j < 8; ++j) dot = fmaf(zv[j], er[lane + 64 * j], dot);
        #pragma unroll
        for (int off = 32; off; off >>= 1) dot += __shfl_xor(dot, off, 64);
        const float d = sqrtf(fmaxf(zn2 + en2[c] - 2.f * dot, 0.f));
        if (lane == t) { mydist = d; myidx = c; }
    }

    float dist[KTOP];
    int   idx[KTOP];
    #pragma unroll
    for (int p = 0; p < KTOP; ++p) {
        float bv = mydist;
        int   bi = myidx;
        #pragma unroll
        for (int off = 32; off; off >>= 1) {
            const float ov = __shfl_xor(bv, off, 64);
            const int   oi = __shfl_xor(bi, off, 64);
            if (ov < bv || (ov == bv && oi < bi)) { bv = ov; bi = oi; }
        }
        dist[p] = bv; idx[p] = bi;
        if (myidx == bi) { mydist = FLT_MAX; myidx = 0x7FFFFFFF; }
    }

    float wgt[KTOP];
    float s = 0.f;
    #pragma unroll
    for (int t = 0; t < KTOP; ++t) {
        wgt[t] = expf((dist[0] - dist[t]) * (1.0f / TEMP_F));
        s += wgt[t];
    }
    const float inv_s = 1.f / s;
    #pragma unroll
    for (int t = 0; t < KTOP; ++t) wgt[t] *= inv_s;

    float lloss = 0.f;
    #pragma unroll
    for (int j = 0; j < 8; ++j) {
        const int d = lane + 64 * j;
        float acc = 0.f;
        #pragma unroll
        for (int t = 0; t < KTOP; ++t)
            acc = fmaf(wgt[t], embed[(size_t)idx[t] * DBASIS + d], acc);
        q_out[(size_t)n * DBASIS + d] = acc;
        const float df = zv[j] - acc;
        lloss = fmaf(df, df, lloss);
    }
    #pragma unroll
    for (int off = 32; off; off >>= 1) lloss += __shfl_xor(lloss, off, 64);

    if (lane == 0) ls[w] = lloss;
    __syncthreads();
    if (tid == 0) atomicAdd(vq_accum, ls[0] + ls[1] + ls[2] + ls[3]);

    #pragma unroll
    for (int t = 0; t < KTOP; ++t)
        if (lane == t) atomicAdd(usage + idx[t], wgt[t] * (1.0f / (float)NROWS));

    if (lane == 0) idx_out[n] = (float)idx[0];
}

// ---------------------------------------------------------------------------
// Finalize: entropy over usage; vq_loss mean
// ---------------------------------------------------------------------------
__global__ __launch_bounds__(256) void k_final(const float* __restrict__ usage,
                                               const float* __restrict__ vq_accum,
                                               float* __restrict__ out_scalars) {
    __shared__ float red[256];
    float s = 0.f;
    for (int c = threadIdx.x; c < CCODES; c += 256) {
        const float u = usage[c];
        s += u * logf(u + 1e-8f);
    }
    red[threadIdx.x] = s;
    __syncthreads();
    for (int st = 128; st; st >>= 1) {
        if (threadIdx.x < st) red[threadIdx.x] += red[threadIdx.x + st];
        __syncthreads();
    }
    if (threadIdx.x == 0) {
        out_scalars[0] = vq_accum[0] * (1.0f / ((float)NROWS * (float)DBASIS));
        out_scalars[1] = -red[0];
    }
}

// ---------------------------------------------------------------------------
extern "C" void kernel_launch(void* const* d_in, const int* in_sizes, int n_in,
                              void* d_out, int out_size, void* d_ws, size_t ws_size,
                              hipStream_t stream) {
    const float* slot  = (const float*)d_in[0];   // [16384][256]
    const float* projW = (const float*)d_in[1];   // [256][512]
    const float* projb = (const float*)d_in[2];   // [512]
    const float* embed = (const float*)d_in[3];   // [1024][512]

    float* out  = (float*)d_out;
    float* q    = out;                            // 16384*512
    float* idxo = out + (size_t)NROWS * DBASIS;   // 16384
    float* scal = idxo + NROWS;                   // 2

    char* wsb = (char*)d_ws;
    float*          Z     = (float*)wsb;          wsb += (size_t)NROWS * DBASIS * 4;   // 32 MB
    float*          P     = (float*)wsb;          wsb += (size_t)NROWS * CCODES * 4;   // 64 MB
    unsigned short* Zh    = (unsigned short*)wsb; wsb += (size_t)NROWS * DBASIS * 2;   // 16 MB
    unsigned short* Zl    = (unsigned short*)wsb; wsb += (size_t)NROWS * DBASIS * 2;   // 16 MB
    unsigned short* Eh    = (unsigned short*)wsb; wsb += (size_t)CCODES * DBASIS * 2;  // 1 MB
    unsigned short* El    = (unsigned short*)wsb; wsb += (size_t)CCODES * DBASIS * 2;  // 1 MB
    float*          en2   = (float*)wsb;          wsb += CCODES * 4;
    float*          usage = (float*)wsb;          wsb += CCODES * 4;
    float*          vq    = (float*)wsb;

    k_prep<<<dim3(CCODES / 256), dim3(256), 0, stream>>>(embed, Eh, El, en2, usage, vq);
    k_gemm_z<<<dim3(NROWS / 128, DBASIS / 128), dim3(256), 0, stream>>>(slot, projW, projb, Z, Zh, Zl);
    // grid = (cols, rows): consecutive blocks share the A row-panel (L2 reuse)
    k_gemm_p<<<dim3(CCODES / 128, NROWS / 128), dim3(256), 0, stream>>>(Zh, Zl, Eh, El, en2, P);
    k_topk<<<dim3(NROWS / 4), dim3(256), 0, stream>>>(P, Z, embed, en2, q, idxo, usage, vq);
    k_final<<<dim3(1), dim3(256), 0, stream>>>(usage, vq, scal);
}

// Round 8
// 361.722 us; speedup vs baseline: 1.1366x; 1.0282x over previous
//
#include <hip/hip_runtime.h>
#include <math.h>
#include <float.h>

// Problem constants (from reference setup_inputs)
#define NROWS  16384   // B*K = 256*64
#define DIN    256
#define DBASIS 512
#define CCODES 1024
#define KTOP   8
#define TEMP_F 0.1f

typedef __attribute__((ext_vector_type(8))) short short8v;  // 8 x bf16 (4 VGPRs)
typedef __attribute__((ext_vector_type(4))) float f32x4;    // MFMA C/D

__device__ __forceinline__ unsigned short bf16_rne(float f) {
    unsigned int u = __float_as_uint(f);
    u += 0x7FFFu + ((u >> 16) & 1u);
    return (unsigned short)(u >> 16);
}
__device__ __forceinline__ float bf16_to_f32(unsigned short h) {
    return __uint_as_float(((unsigned int)h) << 16);
}
// selection key: d2 (non-neg f32, uint-order-isomorphic) with low 10 mantissa
// bits replaced by the code index.
__device__ __forceinline__ unsigned packkey(float p, float zn2, unsigned cidx) {
    const float d2 = fmaxf(p + zn2, 0.f);
    return (__float_as_uint(d2) & 0xFFFFFC00u) | cidx;
}

#define GLOAD16(gsrc, ldst) \
    __builtin_amdgcn_global_load_lds((const __attribute__((address_space(1))) void*)(gsrc), \
                                     (__attribute__((address_space(3))) void*)(ldst), 16, 0, 0)

// ---------------------------------------------------------------------------
// Prep: embed row norms, Eh/El bf16 split, zero usage + vq accumulator
// ---------------------------------------------------------------------------
__global__ __launch_bounds__(256) void k_prep(const float* __restrict__ embed,
                                              unsigned short* __restrict__ Eh,
                                              unsigned short* __restrict__ El,
                                              float* __restrict__ en2,
                                              float* __restrict__ usage,
                                              float* __restrict__ vq_accum) {
    const int c = blockIdx.x * 256 + threadIdx.x;
    const float4* row = (const float4*)(embed + (size_t)c * DBASIS);
    ushort4* ehr = (ushort4*)(Eh + (size_t)c * DBASIS);
    ushort4* elr = (ushort4*)(El + (size_t)c * DBASIS);
    float s = 0.f;
    #pragma unroll 4
    for (int j = 0; j < DBASIS / 4; ++j) {
        const float4 v = row[j];
        s += v.x * v.x + v.y * v.y + v.z * v.z + v.w * v.w;
        ushort4 h, l;
        h.x = bf16_rne(v.x); l.x = bf16_rne(v.x - bf16_to_f32(h.x));
        h.y = bf16_rne(v.y); l.y = bf16_rne(v.y - bf16_to_f32(h.y));
        h.z = bf16_rne(v.z); l.z = bf16_rne(v.z - bf16_to_f32(h.z));
        h.w = bf16_rne(v.w); l.w = bf16_rne(v.w - bf16_to_f32(h.w));
        ehr[j] = h; elr[j] = l;
    }
    en2[c] = s;
    usage[c] = 0.f;
    if (c == 0) vq_accum[0] = 0.f;
}

// ---------------------------------------------------------------------------
// GEMM 1 (NN, f32 VALU — EXACT): Z = slot @ W + b.  M=16384,N=512,K=256.
// 128x128 tile, BK=16, 8x8 micro-tile in quadrants. Math order IDENTICAL to
// the round-3/7 verified kernel (bit-identical Z — indices depend on it).
// New: double-buffered staging; B-tile via global_load_lds (lane-linear,
// unpadded [16][128] — read aliasing is 2-way = free); A-tile global_load
// issued BEFORE compute, ds_write after (T14 split). One barrier per phase.
// ---------------------------------------------------------------------------
__global__ __launch_bounds__(256, 2) void k_gemm_z(const float* __restrict__ A,
                                                   const float* __restrict__ Bm,
                                                   const float* __restrict__ bias,
                                                   float* __restrict__ Z,
                                                   unsigned short* __restrict__ Zh,
                                                   unsigned short* __restrict__ Zl) {
    __shared__ float As[2][16][128];   // 16 KB
    __shared__ float Bs[2][16][128];   // 16 KB
    const int tid = threadIdx.x;
    const int bm = blockIdx.x * 128;
    const int bn = blockIdx.y * 128;
    const int tx = tid & 15, ty = tid >> 4;
    float acc[2][2][4][4] = {};
    float4 a0, a1;

#define LOADA_Z(PH) do {                                                       \
        const int k0_ = (PH) * 16;                                             \
        const int r_ = tid >> 2, c4_ = (tid & 3) * 4;                          \
        a0 = *(const float4*)(A + (size_t)(bm + r_) * DIN + k0_ + c4_);        \
        a1 = *(const float4*)(A + (size_t)(bm + r_ + 64) * DIN + k0_ + c4_);   \
    } while (0)

#define WRITEA_Z(BUF) do {                                                     \
        const int r_ = tid >> 2, c4_ = (tid & 3) * 4;                          \
        As[BUF][c4_ + 0][r_] = a0.x; As[BUF][c4_ + 1][r_] = a0.y;              \
        As[BUF][c4_ + 2][r_] = a0.z; As[BUF][c4_ + 3][r_] = a0.w;              \
        As[BUF][c4_ + 0][r_ + 64] = a1.x; As[BUF][c4_ + 1][r_ + 64] = a1.y;    \
        As[BUF][c4_ + 2][r_ + 64] = a1.z; As[BUF][c4_ + 3][r_ + 64] = a1.w;    \
    } while (0)

#define STAGE_B_Z(BUF, PH) do {                                                \
        const int k0_ = (PH) * 16;                                             \
        _Pragma("unroll")                                                      \
        for (int j_ = 0; j_ < 2; ++j_) {                                       \
            const int gi_ = j_ * 256 + tid;                                    \
            const int r_ = gi_ >> 5;                                           \
            const int c4_ = (gi_ & 31) * 4;                                    \
            GLOAD16(Bm + (size_t)(k0_ + r_) * DBASIS + bn + c4_,               \
                    &Bs[BUF][r_][c4_]);                                        \
        }                                                                      \
    } while (0)

#define COMPUTE_Z(BUF) do {                                                    \
        _Pragma("unroll")                                                      \
        for (int kk = 0; kk < 16; ++kk) {                                      \
            const float4 va0 = *(const float4*)&As[BUF][kk][ty * 4];           \
            const float4 va1 = *(const float4*)&As[BUF][kk][64 + ty * 4];      \
            const float4 vb0 = *(const float4*)&Bs[BUF][kk][tx * 4];           \
            const float4 vb1 = *(const float4*)&Bs[BUF][kk][64 + tx * 4];      \
            const float av[2][4] = {{va0.x, va0.y, va0.z, va0.w},              \
                                    {va1.x, va1.y, va1.z, va1.w}};             \
            const float bv[2][4] = {{vb0.x, vb0.y, vb0.z, vb0.w},              \
                                    {vb1.x, vb1.y, vb1.z, vb1.w}};             \
            _Pragma("unroll")                                                  \
            for (int qi = 0; qi < 2; ++qi)                                     \
                _Pragma("unroll")                                              \
                for (int qj = 0; qj < 2; ++qj)                                 \
                    _Pragma("unroll")                                          \
                    for (int i = 0; i < 4; ++i)                                \
                        _Pragma("unroll")                                      \
                        for (int j = 0; j < 4; ++j)                            \
                            acc[qi][qj][i][j] =                                \
                                fmaf(av[qi][i], bv[qj][j], acc[qi][qj][i][j]); \
        }                                                                      \
    } while (0)

    LOADA_Z(0);
    STAGE_B_Z(0, 0);
    WRITEA_Z(0);
    __syncthreads();
    int cur = 0;
    for (int ph = 0; ph < 15; ++ph) {
        LOADA_Z(ph + 1);
        STAGE_B_Z(cur ^ 1, ph + 1);
        COMPUTE_Z(cur);
        WRITEA_Z(cur ^ 1);
        __syncthreads();
        cur ^= 1;
    }
    COMPUTE_Z(cur);

    #pragma unroll
    for (int qj = 0; qj < 2; ++qj) {
        const int colb = bn + qj * 64 + tx * 4;
        const float4 bv = *(const float4*)(bias + colb);
        const float bb[4] = {bv.x, bv.y, bv.z, bv.w};
        #pragma unroll
        for (int qi = 0; qi < 2; ++qi)
            #pragma unroll
            for (int i = 0; i < 4; ++i) {
                const int row = bm + qi * 64 + ty * 4 + i;
                float4 o;
                o.x = acc[qi][qj][i][0] + bb[0];
                o.y = acc[qi][qj][i][1] + bb[1];
                o.z = acc[qi][qj][i][2] + bb[2];
                o.w = acc[qi][qj][i][3] + bb[3];
                *(float4*)(Z + (size_t)row * DBASIS + colb) = o;
                ushort4 h, l;
                h.x = bf16_rne(o.x); l.x = bf16_rne(o.x - bf16_to_f32(h.x));
                h.y = bf16_rne(o.y); l.y = bf16_rne(o.y - bf16_to_f32(h.y));
                h.z = bf16_rne(o.z); l.z = bf16_rne(o.z - bf16_to_f32(h.z));
                h.w = bf16_rne(o.w); l.w = bf16_rne(o.w - bf16_to_f32(h.w));
                *(ushort4*)(Zh + (size_t)row * DBASIS + colb) = h;
                *(ushort4*)(Zl + (size_t)row * DBASIS + colb) = l;
            }
    }
#undef LOADA_Z
#undef WRITEA_Z
#undef STAGE_B_Z
#undef COMPUTE_Z
}

// ---------------------------------------------------------------------------
// GEMM 2 (MFMA bf16-split NT): Papprox = en2[c] - 2*(Zh.Eh + Zh.El + Zl.Eh)
// BYTE-IDENTICAL to round 7 (PASS) — left alone for clean attribution.
// ---------------------------------------------------------------------------
__global__ __launch_bounds__(256, 2) void k_gemm_p(const unsigned short* __restrict__ Zh,
                                                   const unsigned short* __restrict__ Zl,
                                                   const unsigned short* __restrict__ Eh,
                                                   const unsigned short* __restrict__ El,
                                                   const float* __restrict__ en2,
                                                   float* __restrict__ P) {
    __shared__ __align__(16) short lds[2][4][4096];   // 64 KB: [buf][Ah,Al,Bh,Bl]
    const int tid  = threadIdx.x;
    const int lane = tid & 63;
    const int w    = tid >> 6;
    const int wr   = w >> 1, wc = w & 1;
    const int bm   = blockIdx.y * 128;
    const int bc   = blockIdx.x * 128;
    const int kg   = lane >> 4;
    const int lr   = lane & 15;

    f32x4 acc[4][4];
    #pragma unroll
    for (int i = 0; i < 4; ++i)
        #pragma unroll
        for (int j = 0; j < 4; ++j)
            acc[i][j] = (f32x4){0.f, 0.f, 0.f, 0.f};

#define STAGE_P(BUF, PH) do {                                                  \
        const int k0_ = (PH) * 32;                                             \
        _Pragma("unroll")                                                      \
        for (int j_ = 0; j_ < 2; ++j_) {                                       \
            const int gi_ = j_ * 256 + tid;                                    \
            const int g_  = gi_ >> 7, r_ = gi_ & 127;                          \
            const size_t ao_ = (size_t)(bm + r_) * DBASIS + k0_ + g_ * 8;      \
            const size_t bo_ = (size_t)(bc + r_) * DBASIS + k0_ + g_ * 8;      \
            GLOAD16(Zh + ao_, &lds[BUF][0][gi_ * 8]);                          \
            GLOAD16(Zl + ao_, &lds[BUF][1][gi_ * 8]);                          \
            GLOAD16(Eh + bo_, &lds[BUF][2][gi_ * 8]);                          \
            GLOAD16(El + bo_, &lds[BUF][3][gi_ * 8]);                          \
        }                                                                      \
    } while (0)

#define COMPUTE_P(BUF) do {                                                    \
        short8v afh[4], afl[4], bfh[4], bfl[4];                                \
        _Pragma("unroll")                                                      \
        for (int f = 0; f < 4; ++f) {                                          \
            const int ai = (kg * 128 + wr * 64 + f * 16 + lr) * 8;             \
            const int bi = (kg * 128 + wc * 64 + f * 16 + lr) * 8;             \
            afh[f] = *(const short8v*)&lds[BUF][0][ai];                        \
            afl[f] = *(const short8v*)&lds[BUF][1][ai];                        \
            bfh[f] = *(const short8v*)&lds[BUF][2][bi];                        \
            bfl[f] = *(const short8v*)&lds[BUF][3][bi];                        \
        }                                                                      \
        _Pragma("unroll")                                                      \
        for (int fm = 0; fm < 4; ++fm)                                         \
            _Pragma("unroll")                                                  \
            for (int fn = 0; fn < 4; ++fn) {                                   \
                acc[fm][fn] = __builtin_amdgcn_mfma_f32_16x16x32_bf16(afh[fm], bfh[fn], acc[fm][fn], 0, 0, 0); \
                acc[fm][fn] = __builtin_amdgcn_mfma_f32_16x16x32_bf16(afh[fm], bfl[fn], acc[fm][fn], 0, 0, 0); \
                acc[fm][fn] = __builtin_amdgcn_mfma_f32_16x16x32_bf16(afl[fm], bfh[fn], acc[fm][fn], 0, 0, 0); \
            }                                                                  \
    } while (0)

    STAGE_P(0, 0);
    __syncthreads();
    int cur = 0;
    for (int ph = 0; ph < 15; ++ph) {
        STAGE_P(cur ^ 1, ph + 1);
        COMPUTE_P(cur);
        __syncthreads();
        cur ^= 1;
    }
    COMPUTE_P(cur);

    #pragma unroll
    for (int fn = 0; fn < 4; ++fn) {
        const int col = bc + wc * 64 + fn * 16 + lr;
        const float e2 = en2[col];
        #pragma unroll
        for (int fm = 0; fm < 4; ++fm) {
            const int row0 = bm + wr * 64 + fm * 16 + (lane >> 4) * 4;
            #pragma unroll
            for (int r = 0; r < 4; ++r)
                P[(size_t)(row0 + r) * CCODES + col] = e2 - 2.f * acc[fm][fn][r];
        }
    }
#undef STAGE_P
#undef COMPUTE_P
}

// ---------------------------------------------------------------------------
// Top-k v3: LDS-rank threshold (same T as the binary search, ~5x fewer serial
// steps) + 4-way batched exact refine (identical per-candidate math order
// => bit-identical results). One wave per row, 4 rows per block.
// ---------------------------------------------------------------------------
__global__ __launch_bounds__(256) void k_topk(const float* __restrict__ P,
                                              const float* __restrict__ Z,
                                              const float* __restrict__ embed,
                                              const float* __restrict__ en2,
                                              float* __restrict__ q_out,
                                              float* __restrict__ idx_out,
                                              float* __restrict__ usage,
                                              float* __restrict__ vq_accum) {
    const int tid  = threadIdx.x;
    const int lane = tid & 63;
    const int w    = tid >> 6;
    const int n    = blockIdx.x * 4 + w;

    __shared__ int      cand_lds[4][64];
    __shared__ unsigned km_lds[4][64];
    __shared__ float    ls[4];

    float zv[8];
    float zn2 = 0.f;
    #pragma unroll
    for (int j = 0; j < 8; ++j) {
        zv[j] = Z[(size_t)n * DBASIS + lane + 64 * j];
        zn2 = fmaf(zv[j], zv[j], zn2);
    }
    #pragma unroll
    for (int off = 32; off; off >>= 1) zn2 += __shfl_xor(zn2, off, 64);

    const float4* prow = (const float4*)(P + (size_t)n * CCODES + lane * 16);
    const unsigned cbase = (unsigned)(lane * 16);
    unsigned key[16];
    #pragma unroll
    for (int j = 0; j < 4; ++j) {
        const float4 v = prow[j];
        key[4 * j + 0] = packkey(v.x, zn2, cbase + 4 * j + 0);
        key[4 * j + 1] = packkey(v.y, zn2, cbase + 4 * j + 1);
        key[4 * j + 2] = packkey(v.z, zn2, cbase + 4 * j + 2);
        key[4 * j + 3] = packkey(v.w, zn2, cbase + 4 * j + 3);
    }

    // lane-local min key
    unsigned kmin = key[0];
    #pragma unroll
    for (int t = 1; t < 16; ++t) kmin = (key[t] < kmin) ? key[t] : kmin;

    // T = 16th-smallest lane-min via LDS rank (keys distinct -> unique rank 15).
    // Identical value to the former binary search: smallest T with
    // count(kmin <= T) >= 16.
    km_lds[w][lane] = kmin;
    __syncthreads();
    int rank = 0;
    #pragma unroll
    for (int i = 0; i < 64; ++i) rank += (km_lds[w][i] < kmin) ? 1 : 0;
    const unsigned long long selm = __ballot(rank == 15);
    const int src = (int)(__ffsll((long long)selm) - 1);
    const unsigned T = __shfl(kmin, src, 64);

    // compact candidates (key <= T) into LDS
    int* clist = cand_lds[w];
    int base = 0;
    #pragma unroll
    for (int t = 0; t < 16; ++t) {
        const bool pred = (key[t] <= T);
        const unsigned long long mk = __ballot(pred);
        const int pos = base + __popcll(mk & ((1ull << lane) - 1ull));
        if (pred && pos < 64) clist[pos] = (int)(cbase + t);
        base += __popcll(mk);
    }
    const int m = base < 64 ? base : 64;

    // exact f32 refine, 4 candidates per step (independent chains interleaved;
    // per-candidate op order identical to the serial version)
    float mydist = FLT_MAX;
    int   myidx  = 0x7FFFFFFF;
    for (int t0 = 0; t0 < m; t0 += 4) {
        int cc[4];
        #pragma unroll
        for (int u = 0; u < 4; ++u) {
            const int tt = t0 + u;
            cc[u] = clist[tt < m ? tt : (m - 1)];
        }
        float dot[4] = {0.f, 0.f, 0.f, 0.f};
        #pragma unroll
        for (int j = 0; j < 8; ++j) {
            const int d = lane + 64 * j;
            #pragma unroll
            for (int u = 0; u < 4; ++u)
                dot[u] = fmaf(zv[j], embed[(size_t)cc[u] * DBASIS + d], dot[u]);
        }
        #pragma unroll
        for (int off = 32; off; off >>= 1) {
            #pragma unroll
            for (int u = 0; u < 4; ++u)
                dot[u] += __shfl_xor(dot[u], off, 64);
        }
        #pragma unroll
        for (int u = 0; u < 4; ++u) {
            const int tt = t0 + u;
            const float dd = sqrtf(fmaxf(zn2 + en2[cc[u]] - 2.f * dot[u], 0.f));
            if (tt < m && lane == tt) { mydist = dd; myidx = cc[u]; }
        }
    }

    // exact top-8: butterfly argmin x8 (dist asc, lower code index on ties)
    float dist[KTOP];
    int   idx[KTOP];
    #pragma unroll
    for (int p = 0; p < KTOP; ++p) {
        float bv = mydist;
        int   bi = myidx;
        #pragma unroll
        for (int off = 32; off; off >>= 1) {
            const float ov = __shfl_xor(bv, off, 64);
            const int   oi = __shfl_xor(bi, off, 64);
            if (ov < bv || (ov == bv && oi < bi)) { bv = ov; bi = oi; }
        }
        dist[p] = bv; idx[p] = bi;
        if (myidx == bi) { mydist = FLT_MAX; myidx = 0x7FFFFFFF; }
    }

    float wgt[KTOP];
    float s = 0.f;
    #pragma unroll
    for (int t = 0; t < KTOP; ++t) {
        wgt[t] = expf((dist[0] - dist[t]) * (1.0f / TEMP_F));
        s += wgt[t];
    }
    const float inv_s = 1.f / s;
    #pragma unroll
    for (int t = 0; t < KTOP; ++t) wgt[t] *= inv_s;

    float lloss = 0.f;
    #pragma unroll
    for (int j = 0; j < 8; ++j) {
        const int d = lane + 64 * j;
        float acc = 0.f;
        #pragma unroll
        for (int t = 0; t < KTOP; ++t)
            acc = fmaf(wgt[t], embed[(size_t)idx[t] * DBASIS + d], acc);
        q_out[(size_t)n * DBASIS + d] = acc;
        const float df = zv[j] - acc;
        lloss = fmaf(df, df, lloss);
    }
    #pragma unroll
    for (int off = 32; off; off >>= 1) lloss += __shfl_xor(lloss, off, 64);

    if (lane == 0) ls[w] = lloss;
    __syncthreads();
    if (tid == 0) atomicAdd(vq_accum, ls[0] + ls[1] + ls[2] + ls[3]);

    #pragma unroll
    for (int t = 0; t < KTOP; ++t)
        if (lane == t) atomicAdd(usage + idx[t], wgt[t] * (1.0f / (float)NROWS));

    if (lane == 0) idx_out[n] = (float)idx[0];
}

// ---------------------------------------------------------------------------
// Finalize: entropy over usage; vq_loss mean
// ---------------------------------------------------------------------------
__global__ __launch_bounds__(256) void k_final(const float* __restrict__ usage,
                                               const float* __restrict__ vq_accum,
                                               float* __restrict__ out_scalars) {
    __shared__ float red[256];
    float s = 0.f;
    for (int c = threadIdx.x; c < CCODES; c += 256) {
        const float u = usage[c];
        s += u * logf(u + 1e-8f);
    }
    red[threadIdx.x] = s;
    __syncthreads();
    for (int st = 128; st; st >>= 1) {
        if (threadIdx.x < st) red[threadIdx.x] += red[threadIdx.x + st];
        __syncthreads();
    }
    if (threadIdx.x == 0) {
        out_scalars[0] = vq_accum[0] * (1.0f / ((float)NROWS * (float)DBASIS));
        out_scalars[1] = -red[0];
    }
}

// ---------------------------------------------------------------------------
extern "C" void kernel_launch(void* const* d_in, const int* in_sizes, int n_in,
                              void* d_out, int out_size, void* d_ws, size_t ws_size,
                              hipStream_t stream) {
    const float* slot  = (const float*)d_in[0];   // [16384][256]
    const float* projW = (const float*)d_in[1];   // [256][512]
    const float* projb = (const float*)d_in[2];   // [512]
    const float* embed = (const float*)d_in[3];   // [1024][512]

    float* out  = (float*)d_out;
    float* q    = out;                            // 16384*512
    float* idxo = out + (size_t)NROWS * DBASIS;   // 16384
    float* scal = idxo + NROWS;                   // 2

    char* wsb = (char*)d_ws;
    float*          Z     = (float*)wsb;          wsb += (size_t)NROWS * DBASIS * 4;   // 32 MB
    float*          P     = (float*)wsb;          wsb += (size_t)NROWS * CCODES * 4;   // 64 MB
    unsigned short* Zh    = (unsigned short*)wsb; wsb += (size_t)NROWS * DBASIS * 2;   // 16 MB
    unsigned short* Zl    = (unsigned short*)wsb; wsb += (size_t)NROWS * DBASIS * 2;   // 16 MB
    unsigned short* Eh    = (unsigned short*)wsb; wsb += (size_t)CCODES * DBASIS * 2;  // 1 MB
    unsigned short* El    = (unsigned short*)wsb; wsb += (size_t)CCODES * DBASIS * 2;  // 1 MB
    float*          en2   = (float*)wsb;          wsb += CCODES * 4;
    float*          usage = (float*)wsb;          wsb += CCODES * 4;
    float*          vq    = (float*)wsb;

    k_prep<<<dim3(CCODES / 256), dim3(256), 0, stream>>>(embed, Eh, El, en2, usage, vq);
    k_gemm_z<<<dim3(NROWS / 128, DBASIS / 128), dim3(256), 0, stream>>>(slot, projW, projb, Z, Zh, Zl);
    // grid = (cols, rows): consecutive blocks share the A row-panel (L2 reuse)
    k_gemm_p<<<dim3(CCODES / 128, NROWS / 128), dim3(256), 0, stream>>>(Zh, Zl, Eh, El, en2, P);
    k_topk<<<dim3(NROWS / 4), dim3(256), 0, stream>>>(P, Z, embed, en2, q, idxo, usage, vq);
    k_final<<<dim3(1), dim3(256), 0, stream>>>(usage, vq, scal);
}

// Round 9
// 346.978 us; speedup vs baseline: 1.1849x; 1.0425x over previous
//
#include <hip/hip_runtime.h>
#include <math.h>
#include <float.h>

// Problem constants (from reference setup_inputs)
#define NROWS  16384   // B*K = 256*64
#define DIN    256
#define DBASIS 512
#define CCODES 1024
#define KTOP   8
#define TEMP_F 0.1f

typedef __attribute__((ext_vector_type(8))) short short8v;  // 8 x bf16 (4 VGPRs)
typedef __attribute__((ext_vector_type(4))) float f32x4;    // MFMA C/D

__device__ __forceinline__ unsigned short bf16_rne(float f) {
    unsigned int u = __float_as_uint(f);
    u += 0x7FFFu + ((u >> 16) & 1u);
    return (unsigned short)(u >> 16);
}
__device__ __forceinline__ float bf16_to_f32(unsigned short h) {
    return __uint_as_float(((unsigned int)h) << 16);
}
// selection key: d2 (non-neg f32, uint-order-isomorphic) with low 10 mantissa
// bits replaced by the code index.
__device__ __forceinline__ unsigned packkey(float p, float zn2, unsigned cidx) {
    const float d2 = fmaxf(p + zn2, 0.f);
    return (__float_as_uint(d2) & 0xFFFFFC00u) | cidx;
}

#define GLOAD16(gsrc, ldst) \
    __builtin_amdgcn_global_load_lds((const __attribute__((address_space(1))) void*)(gsrc), \
                                     (__attribute__((address_space(3))) void*)(ldst), 16, 0, 0)

// ---------------------------------------------------------------------------
// Prep: embed row norms, Eh/El bf16 split, zero usage + vq accumulator
// ---------------------------------------------------------------------------
__global__ __launch_bounds__(256) void k_prep(const float* __restrict__ embed,
                                              unsigned short* __restrict__ Eh,
                                              unsigned short* __restrict__ El,
                                              float* __restrict__ en2,
                                              float* __restrict__ usage,
                                              float* __restrict__ vq_accum) {
    const int c = blockIdx.x * 256 + threadIdx.x;
    const float4* row = (const float4*)(embed + (size_t)c * DBASIS);
    ushort4* ehr = (ushort4*)(Eh + (size_t)c * DBASIS);
    ushort4* elr = (ushort4*)(El + (size_t)c * DBASIS);
    float s = 0.f;
    #pragma unroll 4
    for (int j = 0; j < DBASIS / 4; ++j) {
        const float4 v = row[j];
        s += v.x * v.x + v.y * v.y + v.z * v.z + v.w * v.w;
        ushort4 h, l;
        h.x = bf16_rne(v.x); l.x = bf16_rne(v.x - bf16_to_f32(h.x));
        h.y = bf16_rne(v.y); l.y = bf16_rne(v.y - bf16_to_f32(h.y));
        h.z = bf16_rne(v.z); l.z = bf16_rne(v.z - bf16_to_f32(h.z));
        h.w = bf16_rne(v.w); l.w = bf16_rne(v.w - bf16_to_f32(h.w));
        ehr[j] = h; elr[j] = l;
    }
    en2[c] = s;
    usage[c] = 0.f;
    if (c == 0) vq_accum[0] = 0.f;
}

// ---------------------------------------------------------------------------
// GEMM 1 (NN, f32 VALU — EXACT): Z = slot @ W + b.  Byte-identical to round 8.
// ---------------------------------------------------------------------------
__global__ __launch_bounds__(256, 2) void k_gemm_z(const float* __restrict__ A,
                                                   const float* __restrict__ Bm,
                                                   const float* __restrict__ bias,
                                                   float* __restrict__ Z,
                                                   unsigned short* __restrict__ Zh,
                                                   unsigned short* __restrict__ Zl) {
    __shared__ float As[2][16][128];   // 16 KB
    __shared__ float Bs[2][16][128];   // 16 KB
    const int tid = threadIdx.x;
    const int bm = blockIdx.x * 128;
    const int bn = blockIdx.y * 128;
    const int tx = tid & 15, ty = tid >> 4;
    float acc[2][2][4][4] = {};
    float4 a0, a1;

#define LOADA_Z(PH) do {                                                       \
        const int k0_ = (PH) * 16;                                             \
        const int r_ = tid >> 2, c4_ = (tid & 3) * 4;                          \
        a0 = *(const float4*)(A + (size_t)(bm + r_) * DIN + k0_ + c4_);        \
        a1 = *(const float4*)(A + (size_t)(bm + r_ + 64) * DIN + k0_ + c4_);   \
    } while (0)

#define WRITEA_Z(BUF) do {                                                     \
        const int r_ = tid >> 2, c4_ = (tid & 3) * 4;                          \
        As[BUF][c4_ + 0][r_] = a0.x; As[BUF][c4_ + 1][r_] = a0.y;              \
        As[BUF][c4_ + 2][r_] = a0.z; As[BUF][c4_ + 3][r_] = a0.w;              \
        As[BUF][c4_ + 0][r_ + 64] = a1.x; As[BUF][c4_ + 1][r_ + 64] = a1.y;    \
        As[BUF][c4_ + 2][r_ + 64] = a1.z; As[BUF][c4_ + 3][r_ + 64] = a1.w;    \
    } while (0)

#define STAGE_B_Z(BUF, PH) do {                                                \
        const int k0_ = (PH) * 16;                                             \
        _Pragma("unroll")                                                      \
        for (int j_ = 0; j_ < 2; ++j_) {                                       \
            const int gi_ = j_ * 256 + tid;                                    \
            const int r_ = gi_ >> 5;                                           \
            const int c4_ = (gi_ & 31) * 4;                                    \
            GLOAD16(Bm + (size_t)(k0_ + r_) * DBASIS + bn + c4_,               \
                    &Bs[BUF][r_][c4_]);                                        \
        }                                                                      \
    } while (0)

#define COMPUTE_Z(BUF) do {                                                    \
        _Pragma("unroll")                                                      \
        for (int kk = 0; kk < 16; ++kk) {                                      \
            const float4 va0 = *(const float4*)&As[BUF][kk][ty * 4];           \
            const float4 va1 = *(const float4*)&As[BUF][kk][64 + ty * 4];      \
            const float4 vb0 = *(const float4*)&Bs[BUF][kk][tx * 4];           \
            const float4 vb1 = *(const float4*)&Bs[BUF][kk][64 + tx * 4];      \
            const float av[2][4] = {{va0.x, va0.y, va0.z, va0.w},              \
                                    {va1.x, va1.y, va1.z, va1.w}};             \
            const float bv[2][4] = {{vb0.x, vb0.y, vb0.z, vb0.w},              \
                                    {vb1.x, vb1.y, vb1.z, vb1.w}};             \
            _Pragma("unroll")                                                  \
            for (int qi = 0; qi < 2; ++qi)                                     \
                _Pragma("unroll")                                              \
                for (int qj = 0; qj < 2; ++qj)                                 \
                    _Pragma("unroll")                                          \
                    for (int i = 0; i < 4; ++i)                                \
                        _Pragma("unroll")                                      \
                        for (int j = 0; j < 4; ++j)                            \
                            acc[qi][qj][i][j] =                                \
                                fmaf(av[qi][i], bv[qj][j], acc[qi][qj][i][j]); \
        }                                                                      \
    } while (0)

    LOADA_Z(0);
    STAGE_B_Z(0, 0);
    WRITEA_Z(0);
    __syncthreads();
    int cur = 0;
    for (int ph = 0; ph < 15; ++ph) {
        LOADA_Z(ph + 1);
        STAGE_B_Z(cur ^ 1, ph + 1);
        COMPUTE_Z(cur);
        WRITEA_Z(cur ^ 1);
        __syncthreads();
        cur ^= 1;
    }
    COMPUTE_Z(cur);

    #pragma unroll
    for (int qj = 0; qj < 2; ++qj) {
        const int colb = bn + qj * 64 + tx * 4;
        const float4 bv = *(const float4*)(bias + colb);
        const float bb[4] = {bv.x, bv.y, bv.z, bv.w};
        #pragma unroll
        for (int qi = 0; qi < 2; ++qi)
            #pragma unroll
            for (int i = 0; i < 4; ++i) {
                const int row = bm + qi * 64 + ty * 4 + i;
                float4 o;
                o.x = acc[qi][qj][i][0] + bb[0];
                o.y = acc[qi][qj][i][1] + bb[1];
                o.z = acc[qi][qj][i][2] + bb[2];
                o.w = acc[qi][qj][i][3] + bb[3];
                *(float4*)(Z + (size_t)row * DBASIS + colb) = o;
                ushort4 h, l;
                h.x = bf16_rne(o.x); l.x = bf16_rne(o.x - bf16_to_f32(h.x));
                h.y = bf16_rne(o.y); l.y = bf16_rne(o.y - bf16_to_f32(h.y));
                h.z = bf16_rne(o.z); l.z = bf16_rne(o.z - bf16_to_f32(h.z));
                h.w = bf16_rne(o.w); l.w = bf16_rne(o.w - bf16_to_f32(h.w));
                *(ushort4*)(Zh + (size_t)row * DBASIS + colb) = h;
                *(ushort4*)(Zl + (size_t)row * DBASIS + colb) = l;
            }
    }
#undef LOADA_Z
#undef WRITEA_Z
#undef STAGE_B_Z
#undef COMPUTE_Z
}

// ---------------------------------------------------------------------------
// GEMM 2 (MFMA bf16-split NT): Papprox = en2[c] - 2*(Zh.Eh + Zh.El + Zl.Eh)
// NEW this round: counted-vmcnt pipeline (T4) — raw s_barrier + vmcnt(8),
// never drain to 0 in the loop; XCD-aware block swizzle (nwg=1024 % 8 == 0).
// Per-phase: {STAGE(next) -> vmcnt(8) [cur's loads landed, 1 full phase of
// hiding] -> barrier [publish cur] -> ds_read+48 MFMA -> barrier [readers
// done, next overwrite safe]}. Same math order as round 7/8 (bit-identical P).
// ---------------------------------------------------------------------------
__global__ __launch_bounds__(256, 2) void k_gemm_p(const unsigned short* __restrict__ Zh,
                                                   const unsigned short* __restrict__ Zl,
                                                   const unsigned short* __restrict__ Eh,
                                                   const unsigned short* __restrict__ El,
                                                   const float* __restrict__ en2,
                                                   float* __restrict__ P) {
    __shared__ __align__(16) short lds[2][4][4096];   // 64 KB: [buf][Ah,Al,Bh,Bl]
    const int tid  = threadIdx.x;
    const int lane = tid & 63;
    const int w    = tid >> 6;
    const int wr   = w >> 1, wc = w & 1;
    // XCD swizzle: orig%8 = XCD (round-robin dispatch); give each XCD a
    // contiguous chunk of col-fastest (col, row) space -> Z row-panels reused
    // 8x within one XCD's L2, E fully L2-resident.
    const int orig = blockIdx.x;
    const int swz  = (orig & 7) * 128 + (orig >> 3);
    const int bc   = (swz & 7) * 128;
    const int bm   = (swz >> 3) * 128;
    const int kg   = lane >> 4;
    const int lr   = lane & 15;

    f32x4 acc[4][4];
    #pragma unroll
    for (int i = 0; i < 4; ++i)
        #pragma unroll
        for (int j = 0; j < 4; ++j)
            acc[i][j] = (f32x4){0.f, 0.f, 0.f, 0.f};

#define STAGE_P(BUF, PH) do {                                                  \
        const int k0_ = (PH) * 32;                                             \
        _Pragma("unroll")                                                      \
        for (int j_ = 0; j_ < 2; ++j_) {                                       \
            const int gi_ = j_ * 256 + tid;                                    \
            const int g_  = gi_ >> 7, r_ = gi_ & 127;                          \
            const size_t ao_ = (size_t)(bm + r_) * DBASIS + k0_ + g_ * 8;      \
            const size_t bo_ = (size_t)(bc + r_) * DBASIS + k0_ + g_ * 8;      \
            GLOAD16(Zh + ao_, &lds[BUF][0][gi_ * 8]);                          \
            GLOAD16(Zl + ao_, &lds[BUF][1][gi_ * 8]);                          \
            GLOAD16(Eh + bo_, &lds[BUF][2][gi_ * 8]);                          \
            GLOAD16(El + bo_, &lds[BUF][3][gi_ * 8]);                          \
        }                                                                      \
    } while (0)

#define COMPUTE_P(BUF) do {                                                    \
        short8v afh[4], afl[4], bfh[4], bfl[4];                                \
        _Pragma("unroll")                                                      \
        for (int f = 0; f < 4; ++f) {                                          \
            const int ai = (kg * 128 + wr * 64 + f * 16 + lr) * 8;             \
            const int bi = (kg * 128 + wc * 64 + f * 16 + lr) * 8;             \
            afh[f] = *(const short8v*)&lds[BUF][0][ai];                        \
            afl[f] = *(const short8v*)&lds[BUF][1][ai];                        \
            bfh[f] = *(const short8v*)&lds[BUF][2][bi];                        \
            bfl[f] = *(const short8v*)&lds[BUF][3][bi];                        \
        }                                                                      \
        _Pragma("unroll")                                                      \
        for (int fm = 0; fm < 4; ++fm)                                         \
            _Pragma("unroll")                                                  \
            for (int fn = 0; fn < 4; ++fn) {                                   \
                acc[fm][fn] = __builtin_amdgcn_mfma_f32_16x16x32_bf16(afh[fm], bfh[fn], acc[fm][fn], 0, 0, 0); \
                acc[fm][fn] = __builtin_amdgcn_mfma_f32_16x16x32_bf16(afh[fm], bfl[fn], acc[fm][fn], 0, 0, 0); \
                acc[fm][fn] = __builtin_amdgcn_mfma_f32_16x16x32_bf16(afl[fm], bfh[fn], acc[fm][fn], 0, 0, 0); \
            }                                                                  \
    } while (0)

    STAGE_P(0, 0);                                     // 8 loads in flight (buf0)
    int cur = 0;
    for (int ph = 0; ph < 15; ++ph) {
        STAGE_P(cur ^ 1, ph + 1);                      // +8 (buf cur^1) -> 16
        asm volatile("s_waitcnt vmcnt(8)" ::: "memory");  // cur's 8 landed
        __builtin_amdgcn_sched_barrier(0);
        __builtin_amdgcn_s_barrier();                  // all waves: cur ready
        __builtin_amdgcn_sched_barrier(0);
        COMPUTE_P(cur);                                // ds_read (compiler lgkmcnt) + MFMA
        __builtin_amdgcn_s_barrier();                  // all waves done reading cur
        cur ^= 1;
    }
    asm volatile("s_waitcnt vmcnt(0)" ::: "memory");   // drain last buffer
    __builtin_amdgcn_sched_barrier(0);
    __builtin_amdgcn_s_barrier();
    __builtin_amdgcn_sched_barrier(0);
    COMPUTE_P(cur);

    #pragma unroll
    for (int fn = 0; fn < 4; ++fn) {
        const int col = bc + wc * 64 + fn * 16 + lr;
        const float e2 = en2[col];
        #pragma unroll
        for (int fm = 0; fm < 4; ++fm) {
            const int row0 = bm + wr * 64 + fm * 16 + (lane >> 4) * 4;
            #pragma unroll
            for (int r = 0; r < 4; ++r)
                P[(size_t)(row0 + r) * CCODES + col] = e2 - 2.f * acc[fm][fn][r];
        }
    }
#undef STAGE_P
#undef COMPUTE_P
}

// ---------------------------------------------------------------------------
// Top-k v3 (byte-identical to round 8): LDS-rank threshold + 4-way batched
// exact refine + butterfly top-8. One wave per row, 4 rows per block.
// ---------------------------------------------------------------------------
__global__ __launch_bounds__(256) void k_topk(const float* __restrict__ P,
                                              const float* __restrict__ Z,
                                              const float* __restrict__ embed,
                                              const float* __restrict__ en2,
                                              float* __restrict__ q_out,
                                              float* __restrict__ idx_out,
                                              float* __restrict__ usage,
                                              float* __restrict__ vq_accum) {
    const int tid  = threadIdx.x;
    const int lane = tid & 63;
    const int w    = tid >> 6;
    const int n    = blockIdx.x * 4 + w;

    __shared__ int      cand_lds[4][64];
    __shared__ unsigned km_lds[4][64];
    __shared__ float    ls[4];

    float zv[8];
    float zn2 = 0.f;
    #pragma unroll
    for (int j = 0; j < 8; ++j) {
        zv[j] = Z[(size_t)n * DBASIS + lane + 64 * j];
        zn2 = fmaf(zv[j], zv[j], zn2);
    }
    #pragma unroll
    for (int off = 32; off; off >>= 1) zn2 += __shfl_xor(zn2, off, 64);

    const float4* prow = (const float4*)(P + (size_t)n * CCODES + lane * 16);
    const unsigned cbase = (unsigned)(lane * 16);
    unsigned key[16];
    #pragma unroll
    for (int j = 0; j < 4; ++j) {
        const float4 v = prow[j];
        key[4 * j + 0] = packkey(v.x, zn2, cbase + 4 * j + 0);
        key[4 * j + 1] = packkey(v.y, zn2, cbase + 4 * j + 1);
        key[4 * j + 2] = packkey(v.z, zn2, cbase + 4 * j + 2);
        key[4 * j + 3] = packkey(v.w, zn2, cbase + 4 * j + 3);
    }

    unsigned kmin = key[0];
    #pragma unroll
    for (int t = 1; t < 16; ++t) kmin = (key[t] < kmin) ? key[t] : kmin;

    km_lds[w][lane] = kmin;
    __syncthreads();
    int rank = 0;
    #pragma unroll
    for (int i = 0; i < 64; ++i) rank += (km_lds[w][i] < kmin) ? 1 : 0;
    const unsigned long long selm = __ballot(rank == 15);
    const int src = (int)(__ffsll((long long)selm) - 1);
    const unsigned T = __shfl(kmin, src, 64);

    int* clist = cand_lds[w];
    int base = 0;
    #pragma unroll
    for (int t = 0; t < 16; ++t) {
        const bool pred = (key[t] <= T);
        const unsigned long long mk = __ballot(pred);
        const int pos = base + __popcll(mk & ((1ull << lane) - 1ull));
        if (pred && pos < 64) clist[pos] = (int)(cbase + t);
        base += __popcll(mk);
    }
    const int m = base < 64 ? base : 64;

    float mydist = FLT_MAX;
    int   myidx  = 0x7FFFFFFF;
    for (int t0 = 0; t0 < m; t0 += 4) {
        int cc[4];
        #pragma unroll
        for (int u = 0; u < 4; ++u) {
            const int tt = t0 + u;
            cc[u] = clist[tt < m ? tt : (m - 1)];
        }
        float dot[4] = {0.f, 0.f, 0.f, 0.f};
        #pragma unroll
        for (int j = 0; j < 8; ++j) {
            const int d = lane + 64 * j;
            #pragma unroll
            for (int u = 0; u < 4; ++u)
                dot[u] = fmaf(zv[j], embed[(size_t)cc[u] * DBASIS + d], dot[u]);
        }
        #pragma unroll
        for (int off = 32; off; off >>= 1) {
            #pragma unroll
            for (int u = 0; u < 4; ++u)
                dot[u] += __shfl_xor(dot[u], off, 64);
        }
        #pragma unroll
        for (int u = 0; u < 4; ++u) {
            const int tt = t0 + u;
            const float dd = sqrtf(fmaxf(zn2 + en2[cc[u]] - 2.f * dot[u], 0.f));
            if (tt < m && lane == tt) { mydist = dd; myidx = cc[u]; }
        }
    }

    float dist[KTOP];
    int   idx[KTOP];
    #pragma unroll
    for (int p = 0; p < KTOP; ++p) {
        float bv = mydist;
        int   bi = myidx;
        #pragma unroll
        for (int off = 32; off; off >>= 1) {
            const float ov = __shfl_xor(bv, off, 64);
            const int   oi = __shfl_xor(bi, off, 64);
            if (ov < bv || (ov == bv && oi < bi)) { bv = ov; bi = oi; }
        }
        dist[p] = bv; idx[p] = bi;
        if (myidx == bi) { mydist = FLT_MAX; myidx = 0x7FFFFFFF; }
    }

    float wgt[KTOP];
    float s = 0.f;
    #pragma unroll
    for (int t = 0; t < KTOP; ++t) {
        wgt[t] = expf((dist[0] - dist[t]) * (1.0f / TEMP_F));
        s += wgt[t];
    }
    const float inv_s = 1.f / s;
    #pragma unroll
    for (int t = 0; t < KTOP; ++t) wgt[t] *= inv_s;

    float lloss = 0.f;
    #pragma unroll
    for (int j = 0; j < 8; ++j) {
        const int d = lane + 64 * j;
        float acc = 0.f;
        #pragma unroll
        for (int t = 0; t < KTOP; ++t)
            acc = fmaf(wgt[t], embed[(size_t)idx[t] * DBASIS + d], acc);
        q_out[(size_t)n * DBASIS + d] = acc;
        const float df = zv[j] - acc;
        lloss = fmaf(df, df, lloss);
    }
    #pragma unroll
    for (int off = 32; off; off >>= 1) lloss += __shfl_xor(lloss, off, 64);

    if (lane == 0) ls[w] = lloss;
    __syncthreads();
    if (tid == 0) atomicAdd(vq_accum, ls[0] + ls[1] + ls[2] + ls[3]);

    #pragma unroll
    for (int t = 0; t < KTOP; ++t)
        if (lane == t) atomicAdd(usage + idx[t], wgt[t] * (1.0f / (float)NROWS));

    if (lane == 0) idx_out[n] = (float)idx[0];
}

// ---------------------------------------------------------------------------
// Finalize: entropy over usage; vq_loss mean
// ---------------------------------------------------------------------------
__global__ __launch_bounds__(256) void k_final(const float* __restrict__ usage,
                                               const float* __restrict__ vq_accum,
                                               float* __restrict__ out_scalars) {
    __shared__ float red[256];
    float s = 0.f;
    for (int c = threadIdx.x; c < CCODES; c += 256) {
        const float u = usage[c];
        s += u * logf(u + 1e-8f);
    }
    red[threadIdx.x] = s;
    __syncthreads();
    for (int st = 128; st; st >>= 1) {
        if (threadIdx.x < st) red[threadIdx.x] += red[threadIdx.x + st];
        __syncthreads();
    }
    if (threadIdx.x == 0) {
        out_scalars[0] = vq_accum[0] * (1.0f / ((float)NROWS * (float)DBASIS));
        out_scalars[1] = -red[0];
    }
}

// ---------------------------------------------------------------------------
extern "C" void kernel_launch(void* const* d_in, const int* in_sizes, int n_in,
                              void* d_out, int out_size, void* d_ws, size_t ws_size,
                              hipStream_t stream) {
    const float* slot  = (const float*)d_in[0];   // [16384][256]
    const float* projW = (const float*)d_in[1];   // [256][512]
    const float* projb = (const float*)d_in[2];   // [512]
    const float* embed = (const float*)d_in[3];   // [1024][512]

    float* out  = (float*)d_out;
    float* q    = out;                            // 16384*512
    float* idxo = out + (size_t)NROWS * DBASIS;   // 16384
    float* scal = idxo + NROWS;                   // 2

    char* wsb = (char*)d_ws;
    float*          Z     = (float*)wsb;          wsb += (size_t)NROWS * DBASIS * 4;   // 32 MB
    float*          P     = (float*)wsb;          wsb += (size_t)NROWS * CCODES * 4;   // 64 MB
    unsigned short* Zh    = (unsigned short*)wsb; wsb += (size_t)NROWS * DBASIS * 2;   // 16 MB
    unsigned short* Zl    = (unsigned short*)wsb; wsb += (size_t)NROWS * DBASIS * 2;   // 16 MB
    unsigned short* Eh    = (unsigned short*)wsb; wsb += (size_t)CCODES * DBASIS * 2;  // 1 MB
    unsigned short* El    = (unsigned short*)wsb; wsb += (size_t)CCODES * DBASIS * 2;  // 1 MB
    float*          en2   = (float*)wsb;          wsb += CCODES * 4;
    float*          usage = (float*)wsb;          wsb += CCODES * 4;
    float*          vq    = (float*)wsb;

    k_prep<<<dim3(CCODES / 256), dim3(256), 0, stream>>>(embed, Eh, El, en2, usage, vq);
    k_gemm_z<<<dim3(NROWS / 128, DBASIS / 128), dim3(256), 0, stream>>>(slot, projW, projb, Z, Zh, Zl);
    // 1D grid, XCD swizzle + (col,row) decode inside the kernel
    k_gemm_p<<<dim3((NROWS / 128) * (CCODES / 128)), dim3(256), 0, stream>>>(Zh, Zl, Eh, El, en2, P);
    k_topk<<<dim3(NROWS / 4), dim3(256), 0, stream>>>(P, Z, embed, en2, q, idxo, usage, vq);
    k_final<<<dim3(1), dim3(256), 0, stream>>>(usage, vq, scal);
}